// Round 13
// baseline (375.552 us; speedup 1.0000x reference)
//
#include <hip/hip_runtime.h>
#include <hip/hip_bf16.h>
#include <math.h>

#define B_   16
#define L_   2048
#define DIN  512
#define HID_ 512
#define H_   8
#define D_   64
#define U_   40
#define BH   (B_*H_)     // 128

typedef unsigned short u16;
typedef unsigned int u32;
typedef unsigned long long u64;
typedef __bf16 bf16x8 __attribute__((ext_vector_type(8)));
typedef float f32x4 __attribute__((ext_vector_type(4)));

__device__ __forceinline__ u16 f2bf(float x) {            // RNE via HW cvt
  __bf16 b = (__bf16)x;
  return __builtin_bit_cast(unsigned short, b);
}
__device__ __forceinline__ float bf2f(u16 h) {
  return __uint_as_float(((unsigned)h) << 16);
}
__device__ __forceinline__ u32 pk2(float a, float b) {
  return (u32)f2bf(a) | ((u32)f2bf(b) << 16);
}
__device__ __forceinline__ void gload16(const u16* g, u16* l) {
  __builtin_amdgcn_global_load_lds(
      (__attribute__((address_space(1))) void*)(g),
      (__attribute__((address_space(3))) void*)(l), 16, 0, 0);
}
__device__ __forceinline__ void gload16f(const float* g, float* l) {
  __builtin_amdgcn_global_load_lds(
      (__attribute__((address_space(1))) void*)(g),
      (__attribute__((address_space(3))) void*)(l), 16, 0, 0);
}
__device__ __forceinline__ u64 mkkey(float Mv, int l) {
  u32 fb = __float_as_uint(Mv);
  u32 mapped = (fb & 0x80000000u) ? ~fb : (fb | 0x80000000u);
  return ((u64)mapped << 32) | (u64)(0xFFFFFFFFu - (u32)l);
}

// ---------------- weight split+transpose (all 3): W f32 -> Bt3[y] bf16 [512][1024] ---
__global__ __launch_bounds__(256)
void wsplit3_kernel(const float* __restrict__ Wq, const float* __restrict__ Wk,
                    const float* __restrict__ Wv, u16* __restrict__ Bt3) {
  const float* W = (blockIdx.y == 0) ? Wq : (blockIdx.y == 1) ? Wk : Wv;
  u16* Bt = Bt3 + (size_t)blockIdx.y * 524288;
  int tid = blockIdx.x * 256 + threadIdx.x;
  int n = tid & 511, k = tid >> 9;
  float a = W[(size_t)k * 512 + n];
  u16 hi = f2bf(a);
  u16 lo = f2bf(a - bf2f(hi));
  int kb = k >> 5, kc = k & 31;
  int slotH = kc >> 3, wi = kc & 7;
  int swzH = (slotH     ^ (n & 7)) << 3;
  int swzL = ((4+slotH) ^ (n & 7)) << 3;
  Bt[(size_t)n * 1024 + kb * 64 + swzH + wi] = hi;
  Bt[(size_t)n * 1024 + kb * 64 + swzL + wi] = lo;
}

// ---------------- q/k projection: 3-term split, 2-phase double-buffered -------------
// STAGE(next) BEFORE compute(cur); one __syncthreads per kb (its vmcnt(0) drain waits
// on loads that had the whole 48-MFMA compute phase in flight). Bit-identical output
// to the single-buffer version (same converts, same MFMA order).
__global__ __launch_bounds__(256, 2)
void gemm_proj3(const float* __restrict__ A, const u16* __restrict__ Bt,
                float* __restrict__ C) {
  __shared__ float Asf[2][128 * 32];
  __shared__ u16 Bs[2][128 * 64];
  const int bid = blockIdx.x;
  const int g = bid >> 3;
  const int xb = (bid & 7) + ((g >> 2) << 3);
  const int yb = g & 3;
  const int t = threadIdx.x;
  const int w = t >> 6, lane = t & 63;
  const int lhi = lane >> 4, l16 = lane & 15;
  const int row0 = xb * 128, col0 = yb * 128;
  const int wrow = (w >> 1) * 64, wcol = (w & 1) * 64;

  const u16* gB = Bt + (size_t)(col0 + w * 32 + (lane >> 3)) * 1024 + (lane & 7) * 8;
  const int rA0 = w * 32 + (lane >> 3);
  const int swsl = lane & 7;

  f32x4 acc[4][4];
  #pragma unroll
  for (int i = 0; i < 4; ++i)
    #pragma unroll
    for (int j = 0; j < 4; ++j) acc[i][j] = (f32x4){0.f, 0.f, 0.f, 0.f};

#define STAGE3(KB, NB)                                                          \
  { u16* lB = &Bs[NB][(w * 32) * 64];                                           \
    _Pragma("unroll") for (int i = 0; i < 4; ++i)                               \
      gload16(gB + (KB) * 64 + (size_t)i * 8 * 1024, lB + i * 8 * 64);          \
    _Pragma("unroll") for (int i = 0; i < 4; ++i) {                             \
      int r = rA0 + i * 8;                                                      \
      int slot = swsl ^ (r & 7);                                                \
      gload16f(A + (size_t)(row0 + r) * 512 + (KB) * 32 + slot * 4,             \
               &Asf[NB][(w * 32 + i * 8) * 32]); } }

  STAGE3(0, 0)
  __syncthreads();

  for (int kb = 0; kb < 16; ++kb) {
    const int cur = kb & 1;
    if (kb < 15) STAGE3(kb + 1, cur ^ 1)

    bf16x8 bfH[4], bfL[4];
    #pragma unroll
    for (int j = 0; j < 4; ++j) {
      int cb = wcol + j * 16 + l16;
      bfH[j] = *reinterpret_cast<const bf16x8*>(
          &Bs[cur][cb * 64 + ((lhi ^ (cb & 7)) << 3)]);
      bfL[j] = *reinterpret_cast<const bf16x8*>(
          &Bs[cur][cb * 64 + (((4 + lhi) ^ (cb & 7)) << 3)]);
    }
    #pragma unroll
    for (int i = 0; i < 4; ++i) {
      int ra = wrow + i * 16 + l16;
      const f32x4 x0 = *reinterpret_cast<const f32x4*>(
          &Asf[cur][ra * 32 + (((lhi * 2)       ^ (ra & 7)) << 2)]);
      const f32x4 x1 = *reinterpret_cast<const f32x4*>(
          &Asf[cur][ra * 32 + ((((lhi * 2) + 1) ^ (ra & 7)) << 2)]);
      bf16x8 aH;
      aH[0] = (__bf16)x0[0]; aH[1] = (__bf16)x0[1];
      aH[2] = (__bf16)x0[2]; aH[3] = (__bf16)x0[3];
      aH[4] = (__bf16)x1[0]; aH[5] = (__bf16)x1[1];
      aH[6] = (__bf16)x1[2]; aH[7] = (__bf16)x1[3];
      #pragma unroll
      for (int j = 0; j < 4; ++j)
        acc[i][j] = __builtin_amdgcn_mfma_f32_16x16x32_bf16(aH, bfH[j], acc[i][j], 0, 0, 0);
      bf16x8 aL;
      aL[0] = (__bf16)(x0[0] - (float)aH[0]); aL[1] = (__bf16)(x0[1] - (float)aH[1]);
      aL[2] = (__bf16)(x0[2] - (float)aH[2]); aL[3] = (__bf16)(x0[3] - (float)aH[3]);
      aL[4] = (__bf16)(x1[0] - (float)aH[4]); aL[5] = (__bf16)(x1[1] - (float)aH[5]);
      aL[6] = (__bf16)(x1[2] - (float)aH[6]); aL[7] = (__bf16)(x1[3] - (float)aH[7]);
      #pragma unroll
      for (int j = 0; j < 4; ++j)
        acc[i][j] = __builtin_amdgcn_mfma_f32_16x16x32_bf16(aH, bfL[j], acc[i][j], 0, 0, 0);
      #pragma unroll
      for (int j = 0; j < 4; ++j)
        acc[i][j] = __builtin_amdgcn_mfma_f32_16x16x32_bf16(aL, bfH[j], acc[i][j], 0, 0, 0);
    }
    __syncthreads();
  }
#undef STAGE3
  #pragma unroll
  for (int i = 0; i < 4; ++i)
    #pragma unroll
    for (int j = 0; j < 4; ++j)
      #pragma unroll
      for (int r = 0; r < 4; ++r)
        C[(size_t)(row0 + wrow + i * 16 + lhi * 4 + r) * 512
          + col0 + wcol + j * 16 + l16] = acc[i][j][r];
}

// ---------------- v projection: plain bf16, 2-phase double-buffered -----------------
__global__ __launch_bounds__(256, 2)
void gemm_proj_v(const float* __restrict__ A, const u16* __restrict__ Bt,
                 u16* __restrict__ C) {
  __shared__ float Asf[2][128 * 32];
  __shared__ u16 Bs[2][128 * 64];
  const int bid = blockIdx.x;
  const int g = bid >> 3;
  const int xb = (bid & 7) + ((g >> 2) << 3);
  const int yb = g & 3;
  const int t = threadIdx.x;
  const int w = t >> 6, lane = t & 63;
  const int lhi = lane >> 4, l16 = lane & 15;
  const int row0 = xb * 128, col0 = yb * 128;
  const int wrow = (w >> 1) * 64, wcol = (w & 1) * 64;

  const u16* gB = Bt + (size_t)(col0 + w * 32 + (lane >> 3)) * 1024 + (lane & 7) * 8;
  const int rA0 = w * 32 + (lane >> 3);
  const int swsl = lane & 7;

  f32x4 acc[4][4];
  #pragma unroll
  for (int i = 0; i < 4; ++i)
    #pragma unroll
    for (int j = 0; j < 4; ++j) acc[i][j] = (f32x4){0.f, 0.f, 0.f, 0.f};

#define STAGEV(KB, NB)                                                          \
  { u16* lB = &Bs[NB][(w * 32) * 64];                                           \
    _Pragma("unroll") for (int i = 0; i < 4; ++i)                               \
      gload16(gB + (KB) * 64 + (size_t)i * 8 * 1024, lB + i * 8 * 64);          \
    _Pragma("unroll") for (int i = 0; i < 4; ++i) {                             \
      int r = rA0 + i * 8;                                                      \
      int slot = swsl ^ (r & 7);                                                \
      gload16f(A + (size_t)(row0 + r) * 512 + (KB) * 32 + slot * 4,             \
               &Asf[NB][(w * 32 + i * 8) * 32]); } }

  STAGEV(0, 0)
  __syncthreads();

  for (int kb = 0; kb < 16; ++kb) {
    const int cur = kb & 1;
    if (kb < 15) STAGEV(kb + 1, cur ^ 1)
    bf16x8 bfH[4];
    #pragma unroll
    for (int j = 0; j < 4; ++j) {
      int cb = wcol + j * 16 + l16;
      bfH[j] = *reinterpret_cast<const bf16x8*>(
          &Bs[cur][cb * 64 + ((lhi ^ (cb & 7)) << 3)]);
    }
    #pragma unroll
    for (int i = 0; i < 4; ++i) {
      int ra = wrow + i * 16 + l16;
      const f32x4 x0 = *reinterpret_cast<const f32x4*>(
          &Asf[cur][ra * 32 + (((lhi * 2)       ^ (ra & 7)) << 2)]);
      const f32x4 x1 = *reinterpret_cast<const f32x4*>(
          &Asf[cur][ra * 32 + ((((lhi * 2) + 1) ^ (ra & 7)) << 2)]);
      bf16x8 aH;
      aH[0] = (__bf16)x0[0]; aH[1] = (__bf16)x0[1];
      aH[2] = (__bf16)x0[2]; aH[3] = (__bf16)x0[3];
      aH[4] = (__bf16)x1[0]; aH[5] = (__bf16)x1[1];
      aH[6] = (__bf16)x1[2]; aH[7] = (__bf16)x1[3];
      #pragma unroll
      for (int j = 0; j < 4; ++j)
        acc[i][j] = __builtin_amdgcn_mfma_f32_16x16x32_bf16(aH, bfH[j], acc[i][j], 0, 0, 0);
    }
    __syncthreads();
  }
#undef STAGEV
  #pragma unroll
  for (int i = 0; i < 4; ++i)
    #pragma unroll
    for (int j = 0; j < 4; ++j)
      #pragma unroll
      for (int r = 0; r < 4; ++r)
        C[(size_t)(row0 + wrow + i * 16 + lhi * 4 + r) * 512
          + col0 + wcol + j * 16 + l16] = f2bf(acc[i][j][r]);
}

// ---------------- dot + per-chunk top-40 candidates (exact f32) ---------------------
// Wave-local top-40 (barrier-free, wave-synchronous) + single-wave 3-reg merge.
__global__ __launch_bounds__(256)
void dotsel_kernel(const float* __restrict__ qp, const float* __restrict__ kp,
                   const int* __restrict__ indx, u64* __restrict__ cand) {
  __shared__ u64 keys[256];
  __shared__ u64 wl[192];           // 4 lists of 40 at [w*40..w*40+40); pad 160..191 = 0
  const int bh = blockIdx.x, ch = blockIdx.y;
  const int t = threadIdx.x, w = t >> 6, lane = t & 63;
  const size_t boff = (size_t)bh * 131072;
  const int l0 = ch * 256 + w * 64;
  const float cUL = 40.0f / 2048.0f;
  const int li = lane >> 4;
  const int dq = lane & 15;

  if (t >= 160 && t < 192) wl[t] = 0;

  #pragma unroll 4
  for (int i = 0; i < 16; ++i) {
    int l = l0 + i * 4 + li;
    int ls = indx[l];
    float4 q4 = *reinterpret_cast<const float4*>(&qp[boff + (size_t)l * 64 + dq * 4]);
    float4 k4 = *reinterpret_cast<const float4*>(&kp[boff + (size_t)ls * 64 + dq * 4]);
    float p = q4.x * k4.x + q4.y * k4.y + q4.z * k4.z + q4.w * k4.w;
    p += __shfl_xor(p, 1, 64);
    p += __shfl_xor(p, 2, 64);
    p += __shfl_xor(p, 4, 64);
    p += __shfl_xor(p, 8, 64);
    if (dq == 0) {
      float Mv = p - p * cUL;
      keys[w * 64 + i * 4 + li] = mkkey(Mv, l);
    }
  }
  __syncthreads();

  // wave-local top-40 of this wave's 64 keys (descending), no barriers
  u64 myk = keys[t];
  for (int u = 0; u < U_; ++u) {
    u64 b = myk;
    #pragma unroll
    for (int off = 32; off >= 1; off >>= 1) {
      u64 v = __shfl_xor(b, off, 64);
      if (v > b) b = v;
    }
    if (myk == b) myk = 0;
    if (lane == 0) wl[w * 40 + u] = b;
  }
  __syncthreads();

  // wave 0 merges the 4 descending lists -> global top-40 of this chunk
  if (w == 0) {
    u64 c0 = wl[lane], c1 = wl[64 + lane], c2 = wl[128 + lane];
    for (int u = 0; u < U_; ++u) {
      u64 b = c0;
      if (c1 > b) b = c1;
      if (c2 > b) b = c2;
      #pragma unroll
      for (int off = 32; off >= 1; off >>= 1) {
        u64 v = __shfl_xor(b, off, 64);
        if (v > b) b = v;
      }
      if (c0 == b) c0 = 0;
      if (c1 == b) c1 = 0;
      if (c2 == b) c2 = 0;
      if (lane == 0) cand[((size_t)(bh * 8 + ch)) * U_ + u] = b;
    }
  }
}

// ---------------- merge 8x40 candidates -> global top-40 (1 wave per bh) ------------
__global__ __launch_bounds__(64)
void merge_topk(const u64* __restrict__ cand, int* __restrict__ mtop) {
  const int bh = blockIdx.x;
  const int lane = threadIdx.x;
  u64 c0 = cand[(size_t)bh * 320 + 0 * 64 + lane];
  u64 c1 = cand[(size_t)bh * 320 + 1 * 64 + lane];
  u64 c2 = cand[(size_t)bh * 320 + 2 * 64 + lane];
  u64 c3 = cand[(size_t)bh * 320 + 3 * 64 + lane];
  u64 c4 = cand[(size_t)bh * 320 + 4 * 64 + lane];
  for (int u = 0; u < U_; ++u) {
    u64 b = c0;
    if (c1 > b) b = c1;
    if (c2 > b) b = c2;
    if (c3 > b) b = c3;
    if (c4 > b) b = c4;
    #pragma unroll
    for (int off = 32; off >= 1; off >>= 1) {
      u64 v = __shfl_xor(b, off, 64);
      if (v > b) b = v;
    }
    if (c0 == b) c0 = 0;
    if (c1 == b) c1 = 0;
    if (c2 == b) c2 = 0;
    if (c3 == b) c3 = 0;
    if (c4 == b) c4 = 0;
    if (lane == 0) mtop[bh * U_ + u] = (int)(0xFFFFFFFFu - (u32)b);
  }
}

// ---------------- gather selected q rows -> bf16, x0.125, 48-row padded -------------
__global__ __launch_bounds__(256)
void gather_q_kernel(const float* __restrict__ qp, const int* __restrict__ mtop,
                     u16* __restrict__ qredbf) {
  int tid = blockIdx.x * 256 + threadIdx.x;   // BH*48*64 total
  int s = tid >> 6;
  int d = tid & 63;
  int bh = s / 48;
  int u = s - bh * 48;
  float val = 0.f;
  if (u < U_) {
    int m = mtop[bh * U_ + u];
    val = qp[(size_t)bh * (L_ * D_) + (size_t)m * D_ + d] * 0.125f;
  }
  qredbf[tid] = f2bf(val);
}

// ---------------- fused attention chunk: QK^T -> online softmax -> PV partial -------
__global__ __launch_bounds__(256)
void attn_fused(const u16* __restrict__ qredbf, const float* __restrict__ kp,
                const u16* __restrict__ vbf, const int* __restrict__ mtop,
                float* __restrict__ partial, float* __restrict__ msums) {
  __shared__ u16 As[48 * 64];
  __shared__ u16 Bs[128 * 64];      // K tile; reused as V^T [64][128]
  __shared__ u16 Ps[48 * 128];
  __shared__ int ms[48];
  __shared__ float redm[4][48];
  __shared__ float reds[4][48];
  const int bh = blockIdx.x, chk = blockIdx.y;
  const int l0 = chk * 128;
  const int t = threadIdx.x, w = t >> 6, lane = t & 63;
  const int lhi = lane >> 4, l16 = lane & 15;

  for (int e = t; e < 384; e += 256) {
    int r = e >> 3, s = e & 7;
    *reinterpret_cast<uint4*>(&As[r * 64 + ((s ^ (r & 7)) << 3)]) =
        *reinterpret_cast<const uint4*>(&qredbf[(size_t)bh * 3072 + e * 8]);
  }
  #pragma unroll
  for (int ee = 0; ee < 4; ++ee) {
    int e = t + ee * 256;
    int r = e >> 3, s = e & 7;
    const float* src = &kp[(size_t)bh * 131072 + (size_t)(l0 + r) * 64 + s * 8];
    float4 va = *reinterpret_cast<const float4*>(src);
    float4 vb = *reinterpret_cast<const float4*>(src + 4);
    uint4 w4 = make_uint4(pk2(va.x, va.y), pk2(va.z, va.w),
                          pk2(vb.x, vb.y), pk2(vb.z, vb.w));
    *reinterpret_cast<uint4*>(&Bs[r * 64 + ((s ^ (r & 7)) << 3)]) = w4;
  }
  if (t < 48) ms[t] = (t < U_) ? mtop[bh * U_ + t] : -1;
  __syncthreads();

  f32x4 acc[3][2];
  #pragma unroll
  for (int m = 0; m < 3; ++m)
    #pragma unroll
    for (int n = 0; n < 2; ++n) acc[m][n] = (f32x4){0.f, 0.f, 0.f, 0.f};
  #pragma unroll
  for (int ks = 0; ks < 2; ++ks) {
    bf16x8 a[3], b[2];
    #pragma unroll
    for (int m = 0; m < 3; ++m) {
      int r = m * 16 + l16;
      a[m] = *reinterpret_cast<const bf16x8*>(
          &As[r * 64 + (((ks * 4 + lhi) ^ (r & 7)) << 3)]);
    }
    #pragma unroll
    for (int n = 0; n < 2; ++n) {
      int cb = w * 32 + n * 16 + l16;
      b[n] = *reinterpret_cast<const bf16x8*>(
          &Bs[cb * 64 + (((ks * 4 + lhi) ^ (cb & 7)) << 3)]);
    }
    #pragma unroll
    for (int m = 0; m < 3; ++m)
      #pragma unroll
      for (int n = 0; n < 2; ++n)
        acc[m][n] = __builtin_amdgcn_mfma_f32_16x16x32_bf16(a[m], b[n], acc[m][n], 0, 0, 0);
  }

  float val[3][2][4], mx[3][4];
  #pragma unroll
  for (int m = 0; m < 3; ++m)
    #pragma unroll
    for (int r = 0; r < 4; ++r) {
      int u = m * 16 + lhi * 4 + r;
      float v0 = acc[m][0][r], v1 = acc[m][1][r];
      if (l0 + w * 32 + 0 * 16 + l16 > ms[u]) v0 = -INFINITY;
      if (l0 + w * 32 + 1 * 16 + l16 > ms[u]) v1 = -INFINITY;
      val[m][0][r] = v0; val[m][1][r] = v1;
      mx[m][r] = fmaxf(v0, v1);
    }
  #pragma unroll
  for (int off = 1; off <= 8; off <<= 1)
    #pragma unroll
    for (int m = 0; m < 3; ++m)
      #pragma unroll
      for (int r = 0; r < 4; ++r)
        mx[m][r] = fmaxf(mx[m][r], __shfl_xor(mx[m][r], off, 64));
  if (l16 == 0) {
    #pragma unroll
    for (int m = 0; m < 3; ++m)
      #pragma unroll
      for (int r = 0; r < 4; ++r)
        redm[w][m * 16 + lhi * 4 + r] = mx[m][r];
  }
  __syncthreads();

  float sx[3][4];
  #pragma unroll
  for (int m = 0; m < 3; ++m)
    #pragma unroll
    for (int r = 0; r < 4; ++r) {
      int u = m * 16 + lhi * 4 + r;
      float mv = fmaxf(fmaxf(redm[0][u], redm[1][u]), fmaxf(redm[2][u], redm[3][u]));
      mv = (mv > -1e30f) ? mv : 0.f;
      float p0 = __expf(val[m][0][r] - mv);
      float p1 = __expf(val[m][1][r] - mv);
      sx[m][r] = p0 + p1;
      {
        int l = w * 32 + 0 * 16 + l16, s = l >> 3;
        int sw = (s & 8) | ((s & 7) ^ (u & 7));
        Ps[u * 128 + (sw << 3) + (l & 7)] = f2bf(p0);
      }
      {
        int l = w * 32 + 1 * 16 + l16, s = l >> 3;
        int sw = (s & 8) | ((s & 7) ^ (u & 7));
        Ps[u * 128 + (sw << 3) + (l & 7)] = f2bf(p1);
      }
    }
  #pragma unroll
  for (int off = 1; off <= 8; off <<= 1)
    #pragma unroll
    for (int m = 0; m < 3; ++m)
      #pragma unroll
      for (int r = 0; r < 4; ++r)
        sx[m][r] += __shfl_xor(sx[m][r], off, 64);
  if (l16 == 0) {
    #pragma unroll
    for (int m = 0; m < 3; ++m)
      #pragma unroll
      for (int r = 0; r < 4; ++r)
        reds[w][m * 16 + lhi * 4 + r] = sx[m][r];
  }
  __syncthreads();

  if (t < 48) {
    float mv = fmaxf(fmaxf(redm[0][t], redm[1][t]), fmaxf(redm[2][t], redm[3][t]));
    mv = (mv > -1e30f) ? mv : 0.f;
    float sv = reds[0][t] + reds[1][t] + reds[2][t] + reds[3][t];
    size_t o = (((size_t)chk * 128 + bh) * 48 + t) * 2;
    msums[o] = mv; msums[o + 1] = sv;
  }
  const size_t vbase = (size_t)bh * 131072;
  #pragma unroll
  for (int j = 0; j < 16; ++j) {
    int ll = w * 32 + 2 * j;
    u16 ua = vbf[vbase + (size_t)(l0 + ll) * 64 + lane];
    u16 ub = vbf[vbase + (size_t)(l0 + ll + 1) * 64 + lane];
    u32 pk = (u32)ua | ((u32)ub << 16);
    int s = ll >> 3;
    int sw = (s & 8) | ((s & 7) ^ (lane & 7));
    *reinterpret_cast<u32*>(&Bs[lane * 128 + (sw << 3) + (ll & 7)]) = pk;
  }
  __syncthreads();

  f32x4 acc2[3];
  #pragma unroll
  for (int m = 0; m < 3; ++m) acc2[m] = (f32x4){0.f, 0.f, 0.f, 0.f};
  #pragma unroll
  for (int ks = 0; ks < 4; ++ks) {
    bf16x8 b;
    { int cb = w * 16 + l16; int s = ks * 4 + lhi;
      int sw = (s & 8) | ((s & 7) ^ (cb & 7));
      b = *reinterpret_cast<const bf16x8*>(&Bs[cb * 128 + (sw << 3)]); }
    #pragma unroll
    for (int m = 0; m < 3; ++m) {
      int r = m * 16 + l16; int s = ks * 4 + lhi;
      int sw = (s & 8) | ((s & 7) ^ (r & 7));
      bf16x8 a = *reinterpret_cast<const bf16x8*>(&Ps[r * 128 + (sw << 3)]);
      acc2[m] = __builtin_amdgcn_mfma_f32_16x16x32_bf16(a, b, acc2[m], 0, 0, 0);
    }
  }
  #pragma unroll
  for (int m = 0; m < 3; ++m)
    #pragma unroll
    for (int r = 0; r < 4; ++r) {
      int u = m * 16 + lhi * 4 + r;
      partial[(((size_t)chk * 128 + bh) * 48 + u) * 64 + w * 16 + l16] = acc2[m][r];
    }
}

// ---------------- merge 16 chunk-partials with softmax rescale -> upd ---------------
__global__ __launch_bounds__(256)
void merge_pv(const float* __restrict__ partial, const float* __restrict__ msums,
              float* __restrict__ upd) {
  int tid = blockIdx.x * 256 + threadIdx.x;   // BH*U_*64
  int s = tid >> 6, d = tid & 63;
  int bh = s / U_, u = s - bh * U_;
  float mg = -INFINITY;
  #pragma unroll
  for (int c = 0; c < 16; ++c)
    mg = fmaxf(mg, msums[(((size_t)c * 128 + bh) * 48 + u) * 2]);
  float av = 0.f, sg = 0.f;
  #pragma unroll
  for (int c = 0; c < 16; ++c) {
    size_t o = (((size_t)c * 128 + bh) * 48 + u) * 2;
    float e = __expf(msums[o] - mg);
    av += partial[(((size_t)c * 128 + bh) * 48 + u) * 64 + d] * e;
    sg += msums[o + 1] * e;
  }
  upd[(size_t)s * 64 + d] = av / sg;
}

// ---------------- cumsum 2-phase over bf16 v -> bf16 ctx ----------------------------
__global__ __launch_bounds__(256)
void cumsumA(const u16* __restrict__ vbf, float* __restrict__ seg32) {
  int bh = blockIdx.x, sg = blockIdx.y;
  int t = threadIdx.x, w = t >> 6, lane = t & 63;
  int g = sg * 4 + w;
  size_t base = (size_t)bh * 131072 + (size_t)g * 32 * 64;
  float s = 0.f;
  for (int i = 0; i < 32; ++i) s += bf2f(vbf[base + i * 64 + lane]);
  seg32[((size_t)bh * 64 + g) * 64 + lane] = s;
}
__global__ __launch_bounds__(256)
void cumsumB(const u16* __restrict__ vbf, const float* __restrict__ seg32,
             u16* __restrict__ ctxbf) {
  int bh = blockIdx.x, sg = blockIdx.y;
  int t = threadIdx.x, w = t >> 6, lane = t & 63;
  int g = sg * 4 + w;
  float run = 0.f;
  for (int s = 0; s < g; ++s) run += seg32[((size_t)bh * 64 + s) * 64 + lane];
  size_t base = (size_t)bh * 131072 + (size_t)g * 32 * 64;
  for (int i = 0; i < 32; ++i) {
    run += bf2f(vbf[base + i * 64 + lane]);
    ctxbf[base + i * 64 + lane] = f2bf(run);
  }
}

// ---------------- scatter upd rows into bf16 ctx ------------------------------------
__global__ __launch_bounds__(256)
void scatter_kernel(const float* __restrict__ upd, const int* __restrict__ mtop,
                    u16* __restrict__ ctxbf) {
  int tid = blockIdx.x * 256 + threadIdx.x;
  int s = tid >> 6;
  if (s >= BH * U_) return;
  int d = tid & 63;
  int bh = s / U_;
  ctxbf[(size_t)bh * 131072 + (size_t)mtop[s] * 64 + d] = f2bf(upd[(size_t)s * 64 + d]);
}

// ---------------- Wo -> bf16, transposed + swizzled: WoT[j][512] --------------------
__global__ __launch_bounds__(256)
void wo_prep(const float* __restrict__ Wo, u16* __restrict__ WoT) {
  int tid = blockIdx.x * 256 + threadIdx.x;   // 32768
  int j = tid >> 9, k = tid & 511;
  float v = Wo[(size_t)k * 64 + j];
  int k0 = k & ~63, ko = k & 63;
  int ks = ko >> 5, kc = ko & 31;
  int slot = (ks * 4 + (kc >> 3)) ^ (j & 7);
  WoT[(size_t)j * 512 + k0 + (slot << 3) + (kc & 7)] = f2bf(v);
}

// ---------------- out GEMM (bf16 ctx): out[M][64] = ctx @ Wo ------------------------
__global__ __launch_bounds__(256, 6)
void gemm_out(const u16* __restrict__ ctxbf, const u16* __restrict__ WoT,
              float* __restrict__ out) {
  __shared__ u16 As[64 * 64];
  __shared__ u16 Bs[64 * 64];
  const int t = threadIdx.x, w = t >> 6, lane = t & 63;
  const int lhi = lane >> 4, l16 = lane & 15;
  const int row0 = blockIdx.x * 64;
  f32x4 acc[4];
  #pragma unroll
  for (int j = 0; j < 4; ++j) acc[j] = (f32x4){0.f, 0.f, 0.f, 0.f};

  for (int k0 = 0; k0 < 512; k0 += 64) {
    #pragma unroll
    for (int ii = 0; ii < 2; ++ii) {
      int e = t + ii * 256;
      int j = e >> 3, s = e & 7;
      gload16(WoT + (size_t)j * 512 + k0 + s * 8, Bs + (size_t)(w * 64 + ii * 256) * 8);
    }
    #pragma unroll
    for (int ii = 0; ii < 2; ++ii) {
      int e = t + ii * 256;
      int r = e >> 3, s = e & 7;
      gload16(ctxbf + (size_t)(row0 + r) * 512 + k0 + (s ^ (r & 7)) * 8,
              As + (size_t)(w * 64 + ii * 256) * 8);
    }
    __syncthreads();
    #pragma unroll
    for (int ks = 0; ks < 2; ++ks) {
      int r = w * 16 + l16;
      bf16x8 a = *reinterpret_cast<const bf16x8*>(
          &As[r * 64 + (((ks * 4 + lhi) ^ (r & 7)) << 3)]);
      #pragma unroll
      for (int jf = 0; jf < 4; ++jf) {
        int cb = jf * 16 + l16;
        bf16x8 b = *reinterpret_cast<const bf16x8*>(
            &Bs[cb * 64 + (((ks * 4 + lhi) ^ (cb & 7)) << 3)]);
        acc[jf] = __builtin_amdgcn_mfma_f32_16x16x32_bf16(a, b, acc[jf], 0, 0, 0);
      }
    }
    __syncthreads();
  }
  #pragma unroll
  for (int jf = 0; jf < 4; ++jf)
    #pragma unroll
    for (int r = 0; r < 4; ++r)
      out[(size_t)(row0 + w * 16 + lhi * 4 + r) * 64 + jf * 16 + l16] = acc[jf][r];
}

extern "C" void kernel_launch(void* const* d_in, const int* in_sizes, int n_in,
                              void* d_out, int out_size, void* d_ws, size_t ws_size,
                              hipStream_t stream) {
  const float* q_in = (const float*)d_in[0];
  const float* k_in = (const float*)d_in[1];
  const float* v_in = (const float*)d_in[2];
  const float* Wq   = (const float*)d_in[3];
  const float* Wk   = (const float*)d_in[4];
  const float* Wv   = (const float*)d_in[5];
  const float* Wo   = (const float*)d_in[6];
  const int*   indx = (const int*)d_in[7];
  float* out = (float*)d_out;

  float* ws = (float*)d_ws;
  float* qp   = ws;                         // [0, 16M) floats
  float* kp   = ws + 16777216;              // [16M, 32M)
  u16*   vbf  = (u16*)(ws + 33554432);      // 16M u16
  u64*   cand = (u64*)(ws + 50331648);      // 40960 u64
  u16*   WoT  = (u16*)cand;                 // after cand dead
  u16*   qredbf = (u16*)(ws + 50593792);
  int*   mtop = (int*)(ws + 50921472);
  u16*   Bt3  = (u16*)d_out;                // d_out scratch; gemm_out overwrites
  // qp region reuse (qp dead after gather_q):
  float* partial = qp;                      // 16*128*48*64 = 6,291,456 f
  float* msums   = qp + 6291456;            // 196,608 f
  float* upd     = qp + 6488064;            // 327,680 f
  // kp region reuse (kp dead after attn_fused):
  u16*   ctxbf = (u16*)kp;                  // 16M u16
  float* seg32 = kp + 8388608;              // 524,288 f

  const int M = B_ * L_;                    // 32768

  wsplit3_kernel<<<dim3(1024, 3), 256, 0, stream>>>(Wq, Wk, Wv, Bt3);

  // projections: q/k exact 3-term split dbuf (f32 out), v plain bf16 dbuf
  gemm_proj3<<<1024, 256, 0, stream>>>(q_in, Bt3, qp);
  gemm_proj3<<<1024, 256, 0, stream>>>(k_in, Bt3 + 524288, kp);
  gemm_proj_v<<<1024, 256, 0, stream>>>(v_in, Bt3 + 1048576, vbf);

  // exact f32 dot + two-level top-40
  dotsel_kernel<<<dim3(BH, 8), 256, 0, stream>>>(qp, kp, indx, cand);
  merge_topk<<<BH, 64, 0, stream>>>(cand, mtop);
  gather_q_kernel<<<(BH * 48 * 64) / 256, 256, 0, stream>>>(qp, mtop, qredbf);

  // fused attention (QK^T + online softmax + PV partial) + rescale-merge
  attn_fused<<<dim3(BH, 16), 256, 0, stream>>>(qredbf, kp, vbf, mtop, partial, msums);
  merge_pv<<<(BH * U_ * 64) / 256, 256, 0, stream>>>(partial, msums, upd);

  // cumsum of v -> bf16 ctx (kp region; kp dead now)
  cumsumA<<<dim3(BH, 16), 256, 0, stream>>>(vbf, seg32);
  cumsumB<<<dim3(BH, 16), 256, 0, stream>>>(vbf, seg32, ctxbf);

  // scatter attention rows into ctx
  scatter_kernel<<<(BH * U_ * 64) / 256, 256, 0, stream>>>(upd, mtop, ctxbf);

  // out = ctx @ Wo (bf16 MFMA) — fully overwrites d_out (incl. Bt3 scratch)
  wo_prep<<<128, 256, 0, stream>>>(Wo, WoT);
  gemm_out<<<M / 64, 256, 0, stream>>>(ctxbf, WoT, out);
}

// Round 14
// 352.284 us; speedup vs baseline: 1.0661x; 1.0661x over previous
//
#include <hip/hip_runtime.h>
#include <hip/hip_bf16.h>
#include <math.h>

#define B_   16
#define L_   2048
#define DIN  512
#define HID_ 512
#define H_   8
#define D_   64
#define U_   40
#define BH   (B_*H_)     // 128

typedef unsigned short u16;
typedef unsigned int u32;
typedef unsigned long long u64;
typedef __bf16 bf16x8 __attribute__((ext_vector_type(8)));
typedef float f32x4 __attribute__((ext_vector_type(4)));

__device__ __forceinline__ u16 f2bf(float x) {            // RNE via HW cvt
  __bf16 b = (__bf16)x;
  return __builtin_bit_cast(unsigned short, b);
}
__device__ __forceinline__ float bf2f(u16 h) {
  return __uint_as_float(((unsigned)h) << 16);
}
__device__ __forceinline__ u32 pk2(float a, float b) {
  return (u32)f2bf(a) | ((u32)f2bf(b) << 16);
}
__device__ __forceinline__ void gload16(const u16* g, u16* l) {
  __builtin_amdgcn_global_load_lds(
      (__attribute__((address_space(1))) void*)(g),
      (__attribute__((address_space(3))) void*)(l), 16, 0, 0);
}
__device__ __forceinline__ void gload16f(const float* g, float* l) {
  __builtin_amdgcn_global_load_lds(
      (__attribute__((address_space(1))) void*)(g),
      (__attribute__((address_space(3))) void*)(l), 16, 0, 0);
}
__device__ __forceinline__ u64 mkkey(float Mv, int l) {
  u32 fb = __float_as_uint(Mv);
  u32 mapped = (fb & 0x80000000u) ? ~fb : (fb | 0x80000000u);
  return ((u64)mapped << 32) | (u64)(0xFFFFFFFFu - (u32)l);
}

// ---------------- weight split+transpose (all 3): W f32 -> Bt3[y] bf16 [512][1024] ---
__global__ __launch_bounds__(256)
void wsplit3_kernel(const float* __restrict__ Wq, const float* __restrict__ Wk,
                    const float* __restrict__ Wv, u16* __restrict__ Bt3) {
  const float* W = (blockIdx.y == 0) ? Wq : (blockIdx.y == 1) ? Wk : Wv;
  u16* Bt = Bt3 + (size_t)blockIdx.y * 524288;
  int tid = blockIdx.x * 256 + threadIdx.x;
  int n = tid & 511, k = tid >> 9;
  float a = W[(size_t)k * 512 + n];
  u16 hi = f2bf(a);
  u16 lo = f2bf(a - bf2f(hi));
  int kb = k >> 5, kc = k & 31;
  int slotH = kc >> 3, wi = kc & 7;
  int swzH = (slotH     ^ (n & 7)) << 3;
  int swzL = ((4+slotH) ^ (n & 7)) << 3;
  Bt[(size_t)n * 1024 + kb * 64 + swzH + wi] = hi;
  Bt[(size_t)n * 1024 + kb * 64 + swzL + wi] = lo;
}

// ---------------- q/k projection: 3-term split, single-buffer (proven 66us) ---------
// A raw-f32 via global_load_lds (source-swizzled), in-reg hi/lo split co-issued
// with MFMA, XCD-aware 1-D grid decode. VGPR 64 + 64 AGPR -> 4 blocks/CU.
__global__ __launch_bounds__(256, 4)
void gemm_proj3(const float* __restrict__ A, const u16* __restrict__ Bt,
                float* __restrict__ C) {
  __shared__ float Asf[128 * 32];
  __shared__ u16 Bs[128 * 64];
  const int bid = blockIdx.x;
  const int g = bid >> 3;
  const int xb = (bid & 7) + ((g >> 2) << 3);
  const int yb = g & 3;
  const int t = threadIdx.x;
  const int w = t >> 6, lane = t & 63;
  const int lhi = lane >> 4, l16 = lane & 15;
  const int row0 = xb * 128, col0 = yb * 128;
  const int wrow = (w >> 1) * 64, wcol = (w & 1) * 64;

  const u16* gB = Bt + (size_t)(col0 + w * 32 + (lane >> 3)) * 1024 + (lane & 7) * 8;
  u16* lB = &Bs[(w * 32) * 64];
  const int rA0 = w * 32 + (lane >> 3);
  const int swsl = lane & 7;

  f32x4 acc[4][4];
  #pragma unroll
  for (int i = 0; i < 4; ++i)
    #pragma unroll
    for (int j = 0; j < 4; ++j) acc[i][j] = (f32x4){0.f, 0.f, 0.f, 0.f};

  for (int kb = 0; kb < 16; ++kb) {
    #pragma unroll
    for (int i = 0; i < 4; ++i)
      gload16(gB + kb * 64 + (size_t)i * 8 * 1024, lB + i * 8 * 64);
    #pragma unroll
    for (int i = 0; i < 4; ++i) {
      int r = rA0 + i * 8;
      int slot = swsl ^ (r & 7);
      gload16f(A + (size_t)(row0 + r) * 512 + kb * 32 + slot * 4,
               &Asf[(w * 32 + i * 8) * 32]);
    }
    __syncthreads();

    bf16x8 bfH[4], bfL[4];
    #pragma unroll
    for (int j = 0; j < 4; ++j) {
      int cb = wcol + j * 16 + l16;
      bfH[j] = *reinterpret_cast<const bf16x8*>(
          &Bs[cb * 64 + ((lhi ^ (cb & 7)) << 3)]);
      bfL[j] = *reinterpret_cast<const bf16x8*>(
          &Bs[cb * 64 + (((4 + lhi) ^ (cb & 7)) << 3)]);
    }
    #pragma unroll
    for (int i = 0; i < 4; ++i) {
      int ra = wrow + i * 16 + l16;
      const f32x4 x0 = *reinterpret_cast<const f32x4*>(
          &Asf[ra * 32 + (((lhi * 2)       ^ (ra & 7)) << 2)]);
      const f32x4 x1 = *reinterpret_cast<const f32x4*>(
          &Asf[ra * 32 + ((((lhi * 2) + 1) ^ (ra & 7)) << 2)]);
      bf16x8 aH;
      aH[0] = (__bf16)x0[0]; aH[1] = (__bf16)x0[1];
      aH[2] = (__bf16)x0[2]; aH[3] = (__bf16)x0[3];
      aH[4] = (__bf16)x1[0]; aH[5] = (__bf16)x1[1];
      aH[6] = (__bf16)x1[2]; aH[7] = (__bf16)x1[3];
      #pragma unroll
      for (int j = 0; j < 4; ++j)
        acc[i][j] = __builtin_amdgcn_mfma_f32_16x16x32_bf16(aH, bfH[j], acc[i][j], 0, 0, 0);
      bf16x8 aL;
      aL[0] = (__bf16)(x0[0] - (float)aH[0]); aL[1] = (__bf16)(x0[1] - (float)aH[1]);
      aL[2] = (__bf16)(x0[2] - (float)aH[2]); aL[3] = (__bf16)(x0[3] - (float)aH[3]);
      aL[4] = (__bf16)(x1[0] - (float)aH[4]); aL[5] = (__bf16)(x1[1] - (float)aH[5]);
      aL[6] = (__bf16)(x1[2] - (float)aH[6]); aL[7] = (__bf16)(x1[3] - (float)aH[7]);
      #pragma unroll
      for (int j = 0; j < 4; ++j)
        acc[i][j] = __builtin_amdgcn_mfma_f32_16x16x32_bf16(aH, bfL[j], acc[i][j], 0, 0, 0);
      #pragma unroll
      for (int j = 0; j < 4; ++j)
        acc[i][j] = __builtin_amdgcn_mfma_f32_16x16x32_bf16(aL, bfH[j], acc[i][j], 0, 0, 0);
    }
    __syncthreads();
  }
  #pragma unroll
  for (int i = 0; i < 4; ++i)
    #pragma unroll
    for (int j = 0; j < 4; ++j)
      #pragma unroll
      for (int r = 0; r < 4; ++r)
        C[(size_t)(row0 + wrow + i * 16 + lhi * 4 + r) * 512
          + col0 + wcol + j * 16 + l16] = acc[i][j][r];
}

// ---------------- v projection: plain bf16, 2-phase double-buffered -----------------
__global__ __launch_bounds__(256, 2)
void gemm_proj_v(const float* __restrict__ A, const u16* __restrict__ Bt,
                 u16* __restrict__ C) {
  __shared__ float Asf[2][128 * 32];
  __shared__ u16 Bs[2][128 * 64];
  const int bid = blockIdx.x;
  const int g = bid >> 3;
  const int xb = (bid & 7) + ((g >> 2) << 3);
  const int yb = g & 3;
  const int t = threadIdx.x;
  const int w = t >> 6, lane = t & 63;
  const int lhi = lane >> 4, l16 = lane & 15;
  const int row0 = xb * 128, col0 = yb * 128;
  const int wrow = (w >> 1) * 64, wcol = (w & 1) * 64;

  const u16* gB = Bt + (size_t)(col0 + w * 32 + (lane >> 3)) * 1024 + (lane & 7) * 8;
  const int rA0 = w * 32 + (lane >> 3);
  const int swsl = lane & 7;

  f32x4 acc[4][4];
  #pragma unroll
  for (int i = 0; i < 4; ++i)
    #pragma unroll
    for (int j = 0; j < 4; ++j) acc[i][j] = (f32x4){0.f, 0.f, 0.f, 0.f};

#define STAGEV(KB, NB)                                                          \
  { u16* lB = &Bs[NB][(w * 32) * 64];                                           \
    _Pragma("unroll") for (int i = 0; i < 4; ++i)                               \
      gload16(gB + (KB) * 64 + (size_t)i * 8 * 1024, lB + i * 8 * 64);          \
    _Pragma("unroll") for (int i = 0; i < 4; ++i) {                             \
      int r = rA0 + i * 8;                                                      \
      int slot = swsl ^ (r & 7);                                                \
      gload16f(A + (size_t)(row0 + r) * 512 + (KB) * 32 + slot * 4,             \
               &Asf[NB][(w * 32 + i * 8) * 32]); } }

  STAGEV(0, 0)
  __syncthreads();

  for (int kb = 0; kb < 16; ++kb) {
    const int cur = kb & 1;
    if (kb < 15) STAGEV(kb + 1, cur ^ 1)
    bf16x8 bfH[4];
    #pragma unroll
    for (int j = 0; j < 4; ++j) {
      int cb = wcol + j * 16 + l16;
      bfH[j] = *reinterpret_cast<const bf16x8*>(
          &Bs[cur][cb * 64 + ((lhi ^ (cb & 7)) << 3)]);
    }
    #pragma unroll
    for (int i = 0; i < 4; ++i) {
      int ra = wrow + i * 16 + l16;
      const f32x4 x0 = *reinterpret_cast<const f32x4*>(
          &Asf[cur][ra * 32 + (((lhi * 2)       ^ (ra & 7)) << 2)]);
      const f32x4 x1 = *reinterpret_cast<const f32x4*>(
          &Asf[cur][ra * 32 + ((((lhi * 2) + 1) ^ (ra & 7)) << 2)]);
      bf16x8 aH;
      aH[0] = (__bf16)x0[0]; aH[1] = (__bf16)x0[1];
      aH[2] = (__bf16)x0[2]; aH[3] = (__bf16)x0[3];
      aH[4] = (__bf16)x1[0]; aH[5] = (__bf16)x1[1];
      aH[6] = (__bf16)x1[2]; aH[7] = (__bf16)x1[3];
      #pragma unroll
      for (int j = 0; j < 4; ++j)
        acc[i][j] = __builtin_amdgcn_mfma_f32_16x16x32_bf16(aH, bfH[j], acc[i][j], 0, 0, 0);
    }
    __syncthreads();
  }
#undef STAGEV
  #pragma unroll
  for (int i = 0; i < 4; ++i)
    #pragma unroll
    for (int j = 0; j < 4; ++j)
      #pragma unroll
      for (int r = 0; r < 4; ++r)
        C[(size_t)(row0 + wrow + i * 16 + lhi * 4 + r) * 512
          + col0 + wcol + j * 16 + l16] = f2bf(acc[i][j][r]);
}

// ---------------- dot + per-chunk top-40 candidates (exact f32) ---------------------
// Wave-local top-40 (barrier-free, wave-synchronous) + single-wave 3-reg merge.
__global__ __launch_bounds__(256)
void dotsel_kernel(const float* __restrict__ qp, const float* __restrict__ kp,
                   const int* __restrict__ indx, u64* __restrict__ cand) {
  __shared__ u64 keys[256];
  __shared__ u64 wl[192];           // 4 lists of 40 at [w*40..w*40+40); pad 160..191 = 0
  const int bh = blockIdx.x, ch = blockIdx.y;
  const int t = threadIdx.x, w = t >> 6, lane = t & 63;
  const size_t boff = (size_t)bh * 131072;
  const int l0 = ch * 256 + w * 64;
  const float cUL = 40.0f / 2048.0f;
  const int li = lane >> 4;
  const int dq = lane & 15;

  if (t >= 160 && t < 192) wl[t] = 0;

  #pragma unroll 4
  for (int i = 0; i < 16; ++i) {
    int l = l0 + i * 4 + li;
    int ls = indx[l];
    float4 q4 = *reinterpret_cast<const float4*>(&qp[boff + (size_t)l * 64 + dq * 4]);
    float4 k4 = *reinterpret_cast<const float4*>(&kp[boff + (size_t)ls * 64 + dq * 4]);
    float p = q4.x * k4.x + q4.y * k4.y + q4.z * k4.z + q4.w * k4.w;
    p += __shfl_xor(p, 1, 64);
    p += __shfl_xor(p, 2, 64);
    p += __shfl_xor(p, 4, 64);
    p += __shfl_xor(p, 8, 64);
    if (dq == 0) {
      float Mv = p - p * cUL;
      keys[w * 64 + i * 4 + li] = mkkey(Mv, l);
    }
  }
  __syncthreads();

  // wave-local top-40 of this wave's 64 keys (descending), no barriers
  u64 myk = keys[t];
  for (int u = 0; u < U_; ++u) {
    u64 b = myk;
    #pragma unroll
    for (int off = 32; off >= 1; off >>= 1) {
      u64 v = __shfl_xor(b, off, 64);
      if (v > b) b = v;
    }
    if (myk == b) myk = 0;
    if (lane == 0) wl[w * 40 + u] = b;
  }
  __syncthreads();

  // wave 0 merges the 4 descending lists -> global top-40 of this chunk
  if (w == 0) {
    u64 c0 = wl[lane], c1 = wl[64 + lane], c2 = wl[128 + lane];
    for (int u = 0; u < U_; ++u) {
      u64 b = c0;
      if (c1 > b) b = c1;
      if (c2 > b) b = c2;
      #pragma unroll
      for (int off = 32; off >= 1; off >>= 1) {
        u64 v = __shfl_xor(b, off, 64);
        if (v > b) b = v;
      }
      if (c0 == b) c0 = 0;
      if (c1 == b) c1 = 0;
      if (c2 == b) c2 = 0;
      if (lane == 0) cand[((size_t)(bh * 8 + ch)) * U_ + u] = b;
    }
  }
}

// ---------------- merge 8x40 candidates -> global top-40 (1 wave per bh) ------------
__global__ __launch_bounds__(64)
void merge_topk(const u64* __restrict__ cand, int* __restrict__ mtop) {
  const int bh = blockIdx.x;
  const int lane = threadIdx.x;
  u64 c0 = cand[(size_t)bh * 320 + 0 * 64 + lane];
  u64 c1 = cand[(size_t)bh * 320 + 1 * 64 + lane];
  u64 c2 = cand[(size_t)bh * 320 + 2 * 64 + lane];
  u64 c3 = cand[(size_t)bh * 320 + 3 * 64 + lane];
  u64 c4 = cand[(size_t)bh * 320 + 4 * 64 + lane];
  for (int u = 0; u < U_; ++u) {
    u64 b = c0;
    if (c1 > b) b = c1;
    if (c2 > b) b = c2;
    if (c3 > b) b = c3;
    if (c4 > b) b = c4;
    #pragma unroll
    for (int off = 32; off >= 1; off >>= 1) {
      u64 v = __shfl_xor(b, off, 64);
      if (v > b) b = v;
    }
    if (c0 == b) c0 = 0;
    if (c1 == b) c1 = 0;
    if (c2 == b) c2 = 0;
    if (c3 == b) c3 = 0;
    if (c4 == b) c4 = 0;
    if (lane == 0) mtop[bh * U_ + u] = (int)(0xFFFFFFFFu - (u32)b);
  }
}

// ---------------- gather selected q rows -> bf16, x0.125, 48-row padded -------------
__global__ __launch_bounds__(256)
void gather_q_kernel(const float* __restrict__ qp, const int* __restrict__ mtop,
                     u16* __restrict__ qredbf) {
  int tid = blockIdx.x * 256 + threadIdx.x;   // BH*48*64 total
  int s = tid >> 6;
  int d = tid & 63;
  int bh = s / 48;
  int u = s - bh * 48;
  float val = 0.f;
  if (u < U_) {
    int m = mtop[bh * U_ + u];
    val = qp[(size_t)bh * (L_ * D_) + (size_t)m * D_ + d] * 0.125f;
  }
  qredbf[tid] = f2bf(val);
}

// ---------------- fused attention chunk: QK^T -> online softmax -> PV partial -------
__global__ __launch_bounds__(256)
void attn_fused(const u16* __restrict__ qredbf, const float* __restrict__ kp,
                const u16* __restrict__ vbf, const int* __restrict__ mtop,
                float* __restrict__ partial, float* __restrict__ msums) {
  __shared__ u16 As[48 * 64];
  __shared__ u16 Bs[128 * 64];      // K tile; reused as V^T [64][128]
  __shared__ u16 Ps[48 * 128];
  __shared__ int ms[48];
  __shared__ float redm[4][48];
  __shared__ float reds[4][48];
  const int bh = blockIdx.x, chk = blockIdx.y;
  const int l0 = chk * 128;
  const int t = threadIdx.x, w = t >> 6, lane = t & 63;
  const int lhi = lane >> 4, l16 = lane & 15;

  for (int e = t; e < 384; e += 256) {
    int r = e >> 3, s = e & 7;
    *reinterpret_cast<uint4*>(&As[r * 64 + ((s ^ (r & 7)) << 3)]) =
        *reinterpret_cast<const uint4*>(&qredbf[(size_t)bh * 3072 + e * 8]);
  }
  #pragma unroll
  for (int ee = 0; ee < 4; ++ee) {
    int e = t + ee * 256;
    int r = e >> 3, s = e & 7;
    const float* src = &kp[(size_t)bh * 131072 + (size_t)(l0 + r) * 64 + s * 8];
    float4 va = *reinterpret_cast<const float4*>(src);
    float4 vb = *reinterpret_cast<const float4*>(src + 4);
    uint4 w4 = make_uint4(pk2(va.x, va.y), pk2(va.z, va.w),
                          pk2(vb.x, vb.y), pk2(vb.z, vb.w));
    *reinterpret_cast<uint4*>(&Bs[r * 64 + ((s ^ (r & 7)) << 3)]) = w4;
  }
  if (t < 48) ms[t] = (t < U_) ? mtop[bh * U_ + t] : -1;
  __syncthreads();

  f32x4 acc[3][2];
  #pragma unroll
  for (int m = 0; m < 3; ++m)
    #pragma unroll
    for (int n = 0; n < 2; ++n) acc[m][n] = (f32x4){0.f, 0.f, 0.f, 0.f};
  #pragma unroll
  for (int ks = 0; ks < 2; ++ks) {
    bf16x8 a[3], b[2];
    #pragma unroll
    for (int m = 0; m < 3; ++m) {
      int r = m * 16 + l16;
      a[m] = *reinterpret_cast<const bf16x8*>(
          &As[r * 64 + (((ks * 4 + lhi) ^ (r & 7)) << 3)]);
    }
    #pragma unroll
    for (int n = 0; n < 2; ++n) {
      int cb = w * 32 + n * 16 + l16;
      b[n] = *reinterpret_cast<const bf16x8*>(
          &Bs[cb * 64 + (((ks * 4 + lhi) ^ (cb & 7)) << 3)]);
    }
    #pragma unroll
    for (int m = 0; m < 3; ++m)
      #pragma unroll
      for (int n = 0; n < 2; ++n)
        acc[m][n] = __builtin_amdgcn_mfma_f32_16x16x32_bf16(a[m], b[n], acc[m][n], 0, 0, 0);
  }

  float val[3][2][4], mx[3][4];
  #pragma unroll
  for (int m = 0; m < 3; ++m)
    #pragma unroll
    for (int r = 0; r < 4; ++r) {
      int u = m * 16 + lhi * 4 + r;
      float v0 = acc[m][0][r], v1 = acc[m][1][r];
      if (l0 + w * 32 + 0 * 16 + l16 > ms[u]) v0 = -INFINITY;
      if (l0 + w * 32 + 1 * 16 + l16 > ms[u]) v1 = -INFINITY;
      val[m][0][r] = v0; val[m][1][r] = v1;
      mx[m][r] = fmaxf(v0, v1);
    }
  #pragma unroll
  for (int off = 1; off <= 8; off <<= 1)
    #pragma unroll
    for (int m = 0; m < 3; ++m)
      #pragma unroll
      for (int r = 0; r < 4; ++r)
        mx[m][r] = fmaxf(mx[m][r], __shfl_xor(mx[m][r], off, 64));
  if (l16 == 0) {
    #pragma unroll
    for (int m = 0; m < 3; ++m)
      #pragma unroll
      for (int r = 0; r < 4; ++r)
        redm[w][m * 16 + lhi * 4 + r] = mx[m][r];
  }
  __syncthreads();

  float sx[3][4];
  #pragma unroll
  for (int m = 0; m < 3; ++m)
    #pragma unroll
    for (int r = 0; r < 4; ++r) {
      int u = m * 16 + lhi * 4 + r;
      float mv = fmaxf(fmaxf(redm[0][u], redm[1][u]), fmaxf(redm[2][u], redm[3][u]));
      mv = (mv > -1e30f) ? mv : 0.f;
      float p0 = __expf(val[m][0][r] - mv);
      float p1 = __expf(val[m][1][r] - mv);
      sx[m][r] = p0 + p1;
      {
        int l = w * 32 + 0 * 16 + l16, s = l >> 3;
        int sw = (s & 8) | ((s & 7) ^ (u & 7));
        Ps[u * 128 + (sw << 3) + (l & 7)] = f2bf(p0);
      }
      {
        int l = w * 32 + 1 * 16 + l16, s = l >> 3;
        int sw = (s & 8) | ((s & 7) ^ (u & 7));
        Ps[u * 128 + (sw << 3) + (l & 7)] = f2bf(p1);
      }
    }
  #pragma unroll
  for (int off = 1; off <= 8; off <<= 1)
    #pragma unroll
    for (int m = 0; m < 3; ++m)
      #pragma unroll
      for (int r = 0; r < 4; ++r)
        sx[m][r] += __shfl_xor(sx[m][r], off, 64);
  if (l16 == 0) {
    #pragma unroll
    for (int m = 0; m < 3; ++m)
      #pragma unroll
      for (int r = 0; r < 4; ++r)
        reds[w][m * 16 + lhi * 4 + r] = sx[m][r];
  }
  __syncthreads();

  if (t < 48) {
    float mv = fmaxf(fmaxf(redm[0][t], redm[1][t]), fmaxf(redm[2][t], redm[3][t]));
    mv = (mv > -1e30f) ? mv : 0.f;
    float sv = reds[0][t] + reds[1][t] + reds[2][t] + reds[3][t];
    size_t o = (((size_t)chk * 128 + bh) * 48 + t) * 2;
    msums[o] = mv; msums[o + 1] = sv;
  }
  const size_t vbase = (size_t)bh * 131072;
  #pragma unroll
  for (int j = 0; j < 16; ++j) {
    int ll = w * 32 + 2 * j;
    u16 ua = vbf[vbase + (size_t)(l0 + ll) * 64 + lane];
    u16 ub = vbf[vbase + (size_t)(l0 + ll + 1) * 64 + lane];
    u32 pk = (u32)ua | ((u32)ub << 16);
    int s = ll >> 3;
    int sw = (s & 8) | ((s & 7) ^ (lane & 7));
    *reinterpret_cast<u32*>(&Bs[lane * 128 + (sw << 3) + (ll & 7)]) = pk;
  }
  __syncthreads();

  f32x4 acc2[3];
  #pragma unroll
  for (int m = 0; m < 3; ++m) acc2[m] = (f32x4){0.f, 0.f, 0.f, 0.f};
  #pragma unroll
  for (int ks = 0; ks < 4; ++ks) {
    bf16x8 b;
    { int cb = w * 16 + l16; int s = ks * 4 + lhi;
      int sw = (s & 8) | ((s & 7) ^ (cb & 7));
      b = *reinterpret_cast<const bf16x8*>(&Bs[cb * 128 + (sw << 3)]); }
    #pragma unroll
    for (int m = 0; m < 3; ++m) {
      int r = m * 16 + l16; int s = ks * 4 + lhi;
      int sw = (s & 8) | ((s & 7) ^ (r & 7));
      bf16x8 a = *reinterpret_cast<const bf16x8*>(&Ps[r * 128 + (sw << 3)]);
      acc2[m] = __builtin_amdgcn_mfma_f32_16x16x32_bf16(a, b, acc2[m], 0, 0, 0);
    }
  }
  #pragma unroll
  for (int m = 0; m < 3; ++m)
    #pragma unroll
    for (int r = 0; r < 4; ++r) {
      int u = m * 16 + lhi * 4 + r;
      partial[(((size_t)chk * 128 + bh) * 48 + u) * 64 + w * 16 + l16] = acc2[m][r];
    }
}

// ---------------- merge 16 chunk-partials with softmax rescale -> upd ---------------
__global__ __launch_bounds__(256)
void merge_pv(const float* __restrict__ partial, const float* __restrict__ msums,
              float* __restrict__ upd) {
  int tid = blockIdx.x * 256 + threadIdx.x;   // BH*U_*64
  int s = tid >> 6, d = tid & 63;
  int bh = s / U_, u = s - bh * U_;
  float mg = -INFINITY;
  #pragma unroll
  for (int c = 0; c < 16; ++c)
    mg = fmaxf(mg, msums[(((size_t)c * 128 + bh) * 48 + u) * 2]);
  float av = 0.f, sg = 0.f;
  #pragma unroll
  for (int c = 0; c < 16; ++c) {
    size_t o = (((size_t)c * 128 + bh) * 48 + u) * 2;
    float e = __expf(msums[o] - mg);
    av += partial[(((size_t)c * 128 + bh) * 48 + u) * 64 + d] * e;
    sg += msums[o + 1] * e;
  }
  upd[(size_t)s * 64 + d] = av / sg;
}

// ---------------- cumsum 2-phase over bf16 v -> bf16 ctx ----------------------------
__global__ __launch_bounds__(256)
void cumsumA(const u16* __restrict__ vbf, float* __restrict__ seg32) {
  int bh = blockIdx.x, sg = blockIdx.y;
  int t = threadIdx.x, w = t >> 6, lane = t & 63;
  int g = sg * 4 + w;
  size_t base = (size_t)bh * 131072 + (size_t)g * 32 * 64;
  float s = 0.f;
  for (int i = 0; i < 32; ++i) s += bf2f(vbf[base + i * 64 + lane]);
  seg32[((size_t)bh * 64 + g) * 64 + lane] = s;
}
__global__ __launch_bounds__(256)
void cumsumB(const u16* __restrict__ vbf, const float* __restrict__ seg32,
             u16* __restrict__ ctxbf) {
  int bh = blockIdx.x, sg = blockIdx.y;
  int t = threadIdx.x, w = t >> 6, lane = t & 63;
  int g = sg * 4 + w;
  float run = 0.f;
  for (int s = 0; s < g; ++s) run += seg32[((size_t)bh * 64 + s) * 64 + lane];
  size_t base = (size_t)bh * 131072 + (size_t)g * 32 * 64;
  for (int i = 0; i < 32; ++i) {
    run += bf2f(vbf[base + i * 64 + lane]);
    ctxbf[base + i * 64 + lane] = f2bf(run);
  }
}

// ---------------- scatter upd rows into bf16 ctx ------------------------------------
__global__ __launch_bounds__(256)
void scatter_kernel(const float* __restrict__ upd, const int* __restrict__ mtop,
                    u16* __restrict__ ctxbf) {
  int tid = blockIdx.x * 256 + threadIdx.x;
  int s = tid >> 6;
  if (s >= BH * U_) return;
  int d = tid & 63;
  int bh = s / U_;
  ctxbf[(size_t)bh * 131072 + (size_t)mtop[s] * 64 + d] = f2bf(upd[(size_t)s * 64 + d]);
}

// ---------------- Wo -> bf16, transposed + swizzled: WoT[j][512] --------------------
__global__ __launch_bounds__(256)
void wo_prep(const float* __restrict__ Wo, u16* __restrict__ WoT) {
  int tid = blockIdx.x * 256 + threadIdx.x;   // 32768
  int j = tid >> 9, k = tid & 511;
  float v = Wo[(size_t)k * 64 + j];
  int k0 = k & ~63, ko = k & 63;
  int ks = ko >> 5, kc = ko & 31;
  int slot = (ks * 4 + (kc >> 3)) ^ (j & 7);
  WoT[(size_t)j * 512 + k0 + (slot << 3) + (kc & 7)] = f2bf(v);
}

// ---------------- out GEMM (bf16 ctx): out[M][64] = ctx @ Wo ------------------------
__global__ __launch_bounds__(256, 6)
void gemm_out(const u16* __restrict__ ctxbf, const u16* __restrict__ WoT,
              float* __restrict__ out) {
  __shared__ u16 As[64 * 64];
  __shared__ u16 Bs[64 * 64];
  const int t = threadIdx.x, w = t >> 6, lane = t & 63;
  const int lhi = lane >> 4, l16 = lane & 15;
  const int row0 = blockIdx.x * 64;
  f32x4 acc[4];
  #pragma unroll
  for (int j = 0; j < 4; ++j) acc[j] = (f32x4){0.f, 0.f, 0.f, 0.f};

  for (int k0 = 0; k0 < 512; k0 += 64) {
    #pragma unroll
    for (int ii = 0; ii < 2; ++ii) {
      int e = t + ii * 256;
      int j = e >> 3, s = e & 7;
      gload16(WoT + (size_t)j * 512 + k0 + s * 8, Bs + (size_t)(w * 64 + ii * 256) * 8);
    }
    #pragma unroll
    for (int ii = 0; ii < 2; ++ii) {
      int e = t + ii * 256;
      int r = e >> 3, s = e & 7;
      gload16(ctxbf + (size_t)(row0 + r) * 512 + k0 + (s ^ (r & 7)) * 8,
              As + (size_t)(w * 64 + ii * 256) * 8);
    }
    __syncthreads();
    #pragma unroll
    for (int ks = 0; ks < 2; ++ks) {
      int r = w * 16 + l16;
      bf16x8 a = *reinterpret_cast<const bf16x8*>(
          &As[r * 64 + (((ks * 4 + lhi) ^ (r & 7)) << 3)]);
      #pragma unroll
      for (int jf = 0; jf < 4; ++jf) {
        int cb = jf * 16 + l16;
        bf16x8 b = *reinterpret_cast<const bf16x8*>(
            &Bs[cb * 64 + (((ks * 4 + lhi) ^ (cb & 7)) << 3)]);
        acc[jf] = __builtin_amdgcn_mfma_f32_16x16x32_bf16(a, b, acc[jf], 0, 0, 0);
      }
    }
    __syncthreads();
  }
  #pragma unroll
  for (int jf = 0; jf < 4; ++jf)
    #pragma unroll
    for (int r = 0; r < 4; ++r)
      out[(size_t)(row0 + w * 16 + lhi * 4 + r) * 64 + jf * 16 + l16] = acc[jf][r];
}

extern "C" void kernel_launch(void* const* d_in, const int* in_sizes, int n_in,
                              void* d_out, int out_size, void* d_ws, size_t ws_size,
                              hipStream_t stream) {
  const float* q_in = (const float*)d_in[0];
  const float* k_in = (const float*)d_in[1];
  const float* v_in = (const float*)d_in[2];
  const float* Wq   = (const float*)d_in[3];
  const float* Wk   = (const float*)d_in[4];
  const float* Wv   = (const float*)d_in[5];
  const float* Wo   = (const float*)d_in[6];
  const int*   indx = (const int*)d_in[7];
  float* out = (float*)d_out;

  float* ws = (float*)d_ws;
  float* qp   = ws;                         // [0, 16M) floats
  float* kp   = ws + 16777216;              // [16M, 32M)
  u16*   vbf  = (u16*)(ws + 33554432);      // 16M u16
  u64*   cand = (u64*)(ws + 50331648);      // 40960 u64
  u16*   WoT  = (u16*)cand;                 // after cand dead
  u16*   qredbf = (u16*)(ws + 50593792);
  int*   mtop = (int*)(ws + 50921472);
  u16*   Bt3  = (u16*)d_out;                // d_out scratch; gemm_out overwrites
  // qp region reuse (qp dead after gather_q):
  float* partial = qp;                      // 16*128*48*64 = 6,291,456 f
  float* msums   = qp + 6291456;            // 196,608 f
  float* upd     = qp + 6488064;            // 327,680 f
  // kp region reuse (kp dead after attn_fused):
  u16*   ctxbf = (u16*)kp;                  // 16M u16
  float* seg32 = kp + 8388608;              // 524,288 f

  const int M = B_ * L_;                    // 32768

  wsplit3_kernel<<<dim3(1024, 3), 256, 0, stream>>>(Wq, Wk, Wv, Bt3);

  // projections: q/k exact 3-term split single-buffer (f32 out), v plain bf16 dbuf
  gemm_proj3<<<1024, 256, 0, stream>>>(q_in, Bt3, qp);
  gemm_proj3<<<1024, 256, 0, stream>>>(k_in, Bt3 + 524288, kp);
  gemm_proj_v<<<1024, 256, 0, stream>>>(v_in, Bt3 + 1048576, vbf);

  // exact f32 dot + two-level top-40
  dotsel_kernel<<<dim3(BH, 8), 256, 0, stream>>>(qp, kp, indx, cand);
  merge_topk<<<BH, 64, 0, stream>>>(cand, mtop);
  gather_q_kernel<<<(BH * 48 * 64) / 256, 256, 0, stream>>>(qp, mtop, qredbf);

  // fused attention (QK^T + online softmax + PV partial) + rescale-merge
  attn_fused<<<dim3(BH, 16), 256, 0, stream>>>(qredbf, kp, vbf, mtop, partial, msums);
  merge_pv<<<(BH * U_ * 64) / 256, 256, 0, stream>>>(partial, msums, upd);

  // cumsum of v -> bf16 ctx (kp region; kp dead now)
  cumsumA<<<dim3(BH, 16), 256, 0, stream>>>(vbf, seg32);
  cumsumB<<<dim3(BH, 16), 256, 0, stream>>>(vbf, seg32, ctxbf);

  // scatter attention rows into ctx
  scatter_kernel<<<(BH * U_ * 64) / 256, 256, 0, stream>>>(upd, mtop, ctxbf);

  // out = ctx @ Wo (bf16 MFMA) — fully overwrites d_out (incl. Bt3 scratch)
  wo_prep<<<128, 256, 0, stream>>>(Wo, WoT);
  gemm_out<<<M / 64, 256, 0, stream>>>(ctxbf, WoT, out);
}

// Round 15
// 342.047 us; speedup vs baseline: 1.0980x; 1.0299x over previous
//
#include <hip/hip_runtime.h>
#include <hip/hip_bf16.h>
#include <math.h>

#define B_   16
#define L_   2048
#define DIN  512
#define HID_ 512
#define H_   8
#define D_   64
#define U_   40
#define BH   (B_*H_)     // 128

typedef unsigned short u16;
typedef unsigned int u32;
typedef unsigned long long u64;
typedef __bf16 bf16x8 __attribute__((ext_vector_type(8)));
typedef float f32x4 __attribute__((ext_vector_type(4)));

__device__ __forceinline__ u16 f2bf(float x) {            // RNE via HW cvt
  __bf16 b = (__bf16)x;
  return __builtin_bit_cast(unsigned short, b);
}
__device__ __forceinline__ float bf2f(u16 h) {
  return __uint_as_float(((unsigned)h) << 16);
}
__device__ __forceinline__ u32 pk2(float a, float b) {
  return (u32)f2bf(a) | ((u32)f2bf(b) << 16);
}
__device__ __forceinline__ void gload16(const u16* g, u16* l) {
  __builtin_amdgcn_global_load_lds(
      (__attribute__((address_space(1))) void*)(g),
      (__attribute__((address_space(3))) void*)(l), 16, 0, 0);
}
__device__ __forceinline__ void gload16f(const float* g, float* l) {
  __builtin_amdgcn_global_load_lds(
      (__attribute__((address_space(1))) void*)(g),
      (__attribute__((address_space(3))) void*)(l), 16, 0, 0);
}
__device__ __forceinline__ u64 mkkey(float Mv, int l) {
  u32 fb = __float_as_uint(Mv);
  u32 mapped = (fb & 0x80000000u) ? ~fb : (fb | 0x80000000u);
  return ((u64)mapped << 32) | (u64)(0xFFFFFFFFu - (u32)l);
}

// ---------------- weight split+transpose (all 3): W f32 -> Bt3[y] bf16 [512][1024] ---
__global__ __launch_bounds__(256)
void wsplit3_kernel(const float* __restrict__ Wq, const float* __restrict__ Wk,
                    const float* __restrict__ Wv, u16* __restrict__ Bt3) {
  const float* W = (blockIdx.y == 0) ? Wq : (blockIdx.y == 1) ? Wk : Wv;
  u16* Bt = Bt3 + (size_t)blockIdx.y * 524288;
  int tid = blockIdx.x * 256 + threadIdx.x;
  int n = tid & 511, k = tid >> 9;
  float a = W[(size_t)k * 512 + n];
  u16 hi = f2bf(a);
  u16 lo = f2bf(a - bf2f(hi));
  int kb = k >> 5, kc = k & 31;
  int slotH = kc >> 3, wi = kc & 7;
  int swzH = (slotH     ^ (n & 7)) << 3;
  int swzL = ((4+slotH) ^ (n & 7)) << 3;
  Bt[(size_t)n * 1024 + kb * 64 + swzH + wi] = hi;
  Bt[(size_t)n * 1024 + kb * 64 + swzL + wi] = lo;
}

// ---------------- q/k projection: 3-term split, single-buffer (proven 66us) ---------
__global__ __launch_bounds__(256, 4)
void gemm_proj3(const float* __restrict__ A, const u16* __restrict__ Bt,
                float* __restrict__ C) {
  __shared__ float Asf[128 * 32];
  __shared__ u16 Bs[128 * 64];
  const int bid = blockIdx.x;
  const int g = bid >> 3;
  const int xb = (bid & 7) + ((g >> 2) << 3);
  const int yb = g & 3;
  const int t = threadIdx.x;
  const int w = t >> 6, lane = t & 63;
  const int lhi = lane >> 4, l16 = lane & 15;
  const int row0 = xb * 128, col0 = yb * 128;
  const int wrow = (w >> 1) * 64, wcol = (w & 1) * 64;

  const u16* gB = Bt + (size_t)(col0 + w * 32 + (lane >> 3)) * 1024 + (lane & 7) * 8;
  u16* lB = &Bs[(w * 32) * 64];
  const int rA0 = w * 32 + (lane >> 3);
  const int swsl = lane & 7;

  f32x4 acc[4][4];
  #pragma unroll
  for (int i = 0; i < 4; ++i)
    #pragma unroll
    for (int j = 0; j < 4; ++j) acc[i][j] = (f32x4){0.f, 0.f, 0.f, 0.f};

  for (int kb = 0; kb < 16; ++kb) {
    #pragma unroll
    for (int i = 0; i < 4; ++i)
      gload16(gB + kb * 64 + (size_t)i * 8 * 1024, lB + i * 8 * 64);
    #pragma unroll
    for (int i = 0; i < 4; ++i) {
      int r = rA0 + i * 8;
      int slot = swsl ^ (r & 7);
      gload16f(A + (size_t)(row0 + r) * 512 + kb * 32 + slot * 4,
               &Asf[(w * 32 + i * 8) * 32]);
    }
    __syncthreads();

    bf16x8 bfH[4], bfL[4];
    #pragma unroll
    for (int j = 0; j < 4; ++j) {
      int cb = wcol + j * 16 + l16;
      bfH[j] = *reinterpret_cast<const bf16x8*>(
          &Bs[cb * 64 + ((lhi ^ (cb & 7)) << 3)]);
      bfL[j] = *reinterpret_cast<const bf16x8*>(
          &Bs[cb * 64 + (((4 + lhi) ^ (cb & 7)) << 3)]);
    }
    #pragma unroll
    for (int i = 0; i < 4; ++i) {
      int ra = wrow + i * 16 + l16;
      const f32x4 x0 = *reinterpret_cast<const f32x4*>(
          &Asf[ra * 32 + (((lhi * 2)       ^ (ra & 7)) << 2)]);
      const f32x4 x1 = *reinterpret_cast<const f32x4*>(
          &Asf[ra * 32 + ((((lhi * 2) + 1) ^ (ra & 7)) << 2)]);
      bf16x8 aH;
      aH[0] = (__bf16)x0[0]; aH[1] = (__bf16)x0[1];
      aH[2] = (__bf16)x0[2]; aH[3] = (__bf16)x0[3];
      aH[4] = (__bf16)x1[0]; aH[5] = (__bf16)x1[1];
      aH[6] = (__bf16)x1[2]; aH[7] = (__bf16)x1[3];
      #pragma unroll
      for (int j = 0; j < 4; ++j)
        acc[i][j] = __builtin_amdgcn_mfma_f32_16x16x32_bf16(aH, bfH[j], acc[i][j], 0, 0, 0);
      bf16x8 aL;
      aL[0] = (__bf16)(x0[0] - (float)aH[0]); aL[1] = (__bf16)(x0[1] - (float)aH[1]);
      aL[2] = (__bf16)(x0[2] - (float)aH[2]); aL[3] = (__bf16)(x0[3] - (float)aH[3]);
      aL[4] = (__bf16)(x1[0] - (float)aH[4]); aL[5] = (__bf16)(x1[1] - (float)aH[5]);
      aL[6] = (__bf16)(x1[2] - (float)aH[6]); aL[7] = (__bf16)(x1[3] - (float)aH[7]);
      #pragma unroll
      for (int j = 0; j < 4; ++j)
        acc[i][j] = __builtin_amdgcn_mfma_f32_16x16x32_bf16(aH, bfL[j], acc[i][j], 0, 0, 0);
      #pragma unroll
      for (int j = 0; j < 4; ++j)
        acc[i][j] = __builtin_amdgcn_mfma_f32_16x16x32_bf16(aL, bfH[j], acc[i][j], 0, 0, 0);
    }
    __syncthreads();
  }
  #pragma unroll
  for (int i = 0; i < 4; ++i)
    #pragma unroll
    for (int j = 0; j < 4; ++j)
      #pragma unroll
      for (int r = 0; r < 4; ++r)
        C[(size_t)(row0 + wrow + i * 16 + lhi * 4 + r) * 512
          + col0 + wcol + j * 16 + l16] = acc[i][j][r];
}

// ---------------- v projection: plain bf16, 2-phase double-buffered -----------------
__global__ __launch_bounds__(256, 2)
void gemm_proj_v(const float* __restrict__ A, const u16* __restrict__ Bt,
                 u16* __restrict__ C) {
  __shared__ float Asf[2][128 * 32];
  __shared__ u16 Bs[2][128 * 64];
  const int bid = blockIdx.x;
  const int g = bid >> 3;
  const int xb = (bid & 7) + ((g >> 2) << 3);
  const int yb = g & 3;
  const int t = threadIdx.x;
  const int w = t >> 6, lane = t & 63;
  const int lhi = lane >> 4, l16 = lane & 15;
  const int row0 = xb * 128, col0 = yb * 128;
  const int wrow = (w >> 1) * 64, wcol = (w & 1) * 64;

  const u16* gB = Bt + (size_t)(col0 + w * 32 + (lane >> 3)) * 1024 + (lane & 7) * 8;
  const int rA0 = w * 32 + (lane >> 3);
  const int swsl = lane & 7;

  f32x4 acc[4][4];
  #pragma unroll
  for (int i = 0; i < 4; ++i)
    #pragma unroll
    for (int j = 0; j < 4; ++j) acc[i][j] = (f32x4){0.f, 0.f, 0.f, 0.f};

#define STAGEV(KB, NB)                                                          \
  { u16* lB = &Bs[NB][(w * 32) * 64];                                           \
    _Pragma("unroll") for (int i = 0; i < 4; ++i)                               \
      gload16(gB + (KB) * 64 + (size_t)i * 8 * 1024, lB + i * 8 * 64);          \
    _Pragma("unroll") for (int i = 0; i < 4; ++i) {                             \
      int r = rA0 + i * 8;                                                      \
      int slot = swsl ^ (r & 7);                                                \
      gload16f(A + (size_t)(row0 + r) * 512 + (KB) * 32 + slot * 4,             \
               &Asf[NB][(w * 32 + i * 8) * 32]); } }

  STAGEV(0, 0)
  __syncthreads();

  for (int kb = 0; kb < 16; ++kb) {
    const int cur = kb & 1;
    if (kb < 15) STAGEV(kb + 1, cur ^ 1)
    bf16x8 bfH[4];
    #pragma unroll
    for (int j = 0; j < 4; ++j) {
      int cb = wcol + j * 16 + l16;
      bfH[j] = *reinterpret_cast<const bf16x8*>(
          &Bs[cur][cb * 64 + ((lhi ^ (cb & 7)) << 3)]);
    }
    #pragma unroll
    for (int i = 0; i < 4; ++i) {
      int ra = wrow + i * 16 + l16;
      const f32x4 x0 = *reinterpret_cast<const f32x4*>(
          &Asf[cur][ra * 32 + (((lhi * 2)       ^ (ra & 7)) << 2)]);
      const f32x4 x1 = *reinterpret_cast<const f32x4*>(
          &Asf[cur][ra * 32 + ((((lhi * 2) + 1) ^ (ra & 7)) << 2)]);
      bf16x8 aH;
      aH[0] = (__bf16)x0[0]; aH[1] = (__bf16)x0[1];
      aH[2] = (__bf16)x0[2]; aH[3] = (__bf16)x0[3];
      aH[4] = (__bf16)x1[0]; aH[5] = (__bf16)x1[1];
      aH[6] = (__bf16)x1[2]; aH[7] = (__bf16)x1[3];
      #pragma unroll
      for (int j = 0; j < 4; ++j)
        acc[i][j] = __builtin_amdgcn_mfma_f32_16x16x32_bf16(aH, bfH[j], acc[i][j], 0, 0, 0);
    }
    __syncthreads();
  }
#undef STAGEV
  #pragma unroll
  for (int i = 0; i < 4; ++i)
    #pragma unroll
    for (int j = 0; j < 4; ++j)
      #pragma unroll
      for (int r = 0; r < 4; ++r)
        C[(size_t)(row0 + wrow + i * 16 + lhi * 4 + r) * 512
          + col0 + wcol + j * 16 + l16] = f2bf(acc[i][j][r]);
}

// ---------------- dot + per-chunk top-40 candidates (exact f32) ---------------------
// Round-11 proven selection (shared wmax, 1 barrier/iter) + unroll-8 load phase.
__global__ __launch_bounds__(256)
void dotsel_kernel(const float* __restrict__ qp, const float* __restrict__ kp,
                   const int* __restrict__ indx, u64* __restrict__ cand) {
  __shared__ u64 keys[256];
  __shared__ u64 wmax[2][4];
  const int bh = blockIdx.x, ch = blockIdx.y;
  const int t = threadIdx.x, w = t >> 6, lane = t & 63;
  const size_t boff = (size_t)bh * 131072;
  const int l0 = ch * 256 + w * 64;
  const float cUL = 40.0f / 2048.0f;
  const int li = lane >> 4;
  const int dq = lane & 15;

  #pragma unroll 8
  for (int i = 0; i < 16; ++i) {
    int l = l0 + i * 4 + li;
    int ls = indx[l];
    float4 q4 = *reinterpret_cast<const float4*>(&qp[boff + (size_t)l * 64 + dq * 4]);
    float4 k4 = *reinterpret_cast<const float4*>(&kp[boff + (size_t)ls * 64 + dq * 4]);
    float p = q4.x * k4.x + q4.y * k4.y + q4.z * k4.z + q4.w * k4.w;
    p += __shfl_xor(p, 1, 64);
    p += __shfl_xor(p, 2, 64);
    p += __shfl_xor(p, 4, 64);
    p += __shfl_xor(p, 8, 64);
    if (dq == 0) {
      float Mv = p - p * cUL;
      keys[w * 64 + i * 4 + li] = mkkey(Mv, l);
    }
  }
  __syncthreads();

  u64 myk = keys[t];
  for (int u = 0; u < U_; ++u) {
    u64 b = myk;
    #pragma unroll
    for (int off = 32; off >= 1; off >>= 1) {
      u64 v = __shfl_xor(b, off, 64);
      if (v > b) b = v;
    }
    if (lane == 0) wmax[u & 1][w] = b;
    __syncthreads();
    const u64* wm = wmax[u & 1];
    u64 m = wm[0];
    if (wm[1] > m) m = wm[1];
    if (wm[2] > m) m = wm[2];
    if (wm[3] > m) m = wm[3];
    if (myk == m) myk = 0;              // unique keys: owner clears
    if (t == 0) cand[((size_t)(bh * 8 + ch)) * U_ + u] = m;
  }
}

// ---------------- merge 8x40 candidates -> global top-40 (1 wave per bh) ------------
__global__ __launch_bounds__(64)
void merge_topk(const u64* __restrict__ cand, int* __restrict__ mtop) {
  const int bh = blockIdx.x;
  const int lane = threadIdx.x;
  u64 c0 = cand[(size_t)bh * 320 + 0 * 64 + lane];
  u64 c1 = cand[(size_t)bh * 320 + 1 * 64 + lane];
  u64 c2 = cand[(size_t)bh * 320 + 2 * 64 + lane];
  u64 c3 = cand[(size_t)bh * 320 + 3 * 64 + lane];
  u64 c4 = cand[(size_t)bh * 320 + 4 * 64 + lane];
  for (int u = 0; u < U_; ++u) {
    u64 b = c0;
    if (c1 > b) b = c1;
    if (c2 > b) b = c2;
    if (c3 > b) b = c3;
    if (c4 > b) b = c4;
    #pragma unroll
    for (int off = 32; off >= 1; off >>= 1) {
      u64 v = __shfl_xor(b, off, 64);
      if (v > b) b = v;
    }
    if (c0 == b) c0 = 0;
    if (c1 == b) c1 = 0;
    if (c2 == b) c2 = 0;
    if (c3 == b) c3 = 0;
    if (c4 == b) c4 = 0;
    if (lane == 0) mtop[bh * U_ + u] = (int)(0xFFFFFFFFu - (u32)b);
  }
}

// ---------------- gather selected q rows -> bf16, x0.125, 48-row padded -------------
__global__ __launch_bounds__(256)
void gather_q_kernel(const float* __restrict__ qp, const int* __restrict__ mtop,
                     u16* __restrict__ qredbf) {
  int tid = blockIdx.x * 256 + threadIdx.x;   // BH*48*64 total
  int s = tid >> 6;
  int d = tid & 63;
  int bh = s / 48;
  int u = s - bh * 48;
  float val = 0.f;
  if (u < U_) {
    int m = mtop[bh * U_ + u];
    val = qp[(size_t)bh * (L_ * D_) + (size_t)m * D_ + d] * 0.125f;
  }
  qredbf[tid] = f2bf(val);
}

// ---------------- fused attention chunk: QK^T -> online softmax -> PV partial -------
__global__ __launch_bounds__(256)
void attn_fused(const u16* __restrict__ qredbf, const float* __restrict__ kp,
                const u16* __restrict__ vbf, const int* __restrict__ mtop,
                float* __restrict__ partial, float* __restrict__ msums) {
  __shared__ u16 As[48 * 64];
  __shared__ u16 Bs[128 * 64];      // K tile; reused as V^T [64][128]
  __shared__ u16 Ps[48 * 128];
  __shared__ int ms[48];
  __shared__ float redm[4][48];
  __shared__ float reds[4][48];
  const int bh = blockIdx.x, chk = blockIdx.y;
  const int l0 = chk * 128;
  const int t = threadIdx.x, w = t >> 6, lane = t & 63;
  const int lhi = lane >> 4, l16 = lane & 15;

  for (int e = t; e < 384; e += 256) {
    int r = e >> 3, s = e & 7;
    *reinterpret_cast<uint4*>(&As[r * 64 + ((s ^ (r & 7)) << 3)]) =
        *reinterpret_cast<const uint4*>(&qredbf[(size_t)bh * 3072 + e * 8]);
  }
  #pragma unroll
  for (int ee = 0; ee < 4; ++ee) {
    int e = t + ee * 256;
    int r = e >> 3, s = e & 7;
    const float* src = &kp[(size_t)bh * 131072 + (size_t)(l0 + r) * 64 + s * 8];
    float4 va = *reinterpret_cast<const float4*>(src);
    float4 vb = *reinterpret_cast<const float4*>(src + 4);
    uint4 w4 = make_uint4(pk2(va.x, va.y), pk2(va.z, va.w),
                          pk2(vb.x, vb.y), pk2(vb.z, vb.w));
    *reinterpret_cast<uint4*>(&Bs[r * 64 + ((s ^ (r & 7)) << 3)]) = w4;
  }
  if (t < 48) ms[t] = (t < U_) ? mtop[bh * U_ + t] : -1;
  __syncthreads();

  f32x4 acc[3][2];
  #pragma unroll
  for (int m = 0; m < 3; ++m)
    #pragma unroll
    for (int n = 0; n < 2; ++n) acc[m][n] = (f32x4){0.f, 0.f, 0.f, 0.f};
  #pragma unroll
  for (int ks = 0; ks < 2; ++ks) {
    bf16x8 a[3], b[2];
    #pragma unroll
    for (int m = 0; m < 3; ++m) {
      int r = m * 16 + l16;
      a[m] = *reinterpret_cast<const bf16x8*>(
          &As[r * 64 + (((ks * 4 + lhi) ^ (r & 7)) << 3)]);
    }
    #pragma unroll
    for (int n = 0; n < 2; ++n) {
      int cb = w * 32 + n * 16 + l16;
      b[n] = *reinterpret_cast<const bf16x8*>(
          &Bs[cb * 64 + (((ks * 4 + lhi) ^ (cb & 7)) << 3)]);
    }
    #pragma unroll
    for (int m = 0; m < 3; ++m)
      #pragma unroll
      for (int n = 0; n < 2; ++n)
        acc[m][n] = __builtin_amdgcn_mfma_f32_16x16x32_bf16(a[m], b[n], acc[m][n], 0, 0, 0);
  }

  float val[3][2][4], mx[3][4];
  #pragma unroll
  for (int m = 0; m < 3; ++m)
    #pragma unroll
    for (int r = 0; r < 4; ++r) {
      int u = m * 16 + lhi * 4 + r;
      float v0 = acc[m][0][r], v1 = acc[m][1][r];
      if (l0 + w * 32 + 0 * 16 + l16 > ms[u]) v0 = -INFINITY;
      if (l0 + w * 32 + 1 * 16 + l16 > ms[u]) v1 = -INFINITY;
      val[m][0][r] = v0; val[m][1][r] = v1;
      mx[m][r] = fmaxf(v0, v1);
    }
  #pragma unroll
  for (int off = 1; off <= 8; off <<= 1)
    #pragma unroll
    for (int m = 0; m < 3; ++m)
      #pragma unroll
      for (int r = 0; r < 4; ++r)
        mx[m][r] = fmaxf(mx[m][r], __shfl_xor(mx[m][r], off, 64));
  if (l16 == 0) {
    #pragma unroll
    for (int m = 0; m < 3; ++m)
      #pragma unroll
      for (int r = 0; r < 4; ++r)
        redm[w][m * 16 + lhi * 4 + r] = mx[m][r];
  }
  __syncthreads();

  float sx[3][4];
  #pragma unroll
  for (int m = 0; m < 3; ++m)
    #pragma unroll
    for (int r = 0; r < 4; ++r) {
      int u = m * 16 + lhi * 4 + r;
      float mv = fmaxf(fmaxf(redm[0][u], redm[1][u]), fmaxf(redm[2][u], redm[3][u]));
      mv = (mv > -1e30f) ? mv : 0.f;
      float p0 = __expf(val[m][0][r] - mv);
      float p1 = __expf(val[m][1][r] - mv);
      sx[m][r] = p0 + p1;
      {
        int l = w * 32 + 0 * 16 + l16, s = l >> 3;
        int sw = (s & 8) | ((s & 7) ^ (u & 7));
        Ps[u * 128 + (sw << 3) + (l & 7)] = f2bf(p0);
      }
      {
        int l = w * 32 + 1 * 16 + l16, s = l >> 3;
        int sw = (s & 8) | ((s & 7) ^ (u & 7));
        Ps[u * 128 + (sw << 3) + (l & 7)] = f2bf(p1);
      }
    }
  #pragma unroll
  for (int off = 1; off <= 8; off <<= 1)
    #pragma unroll
    for (int m = 0; m < 3; ++m)
      #pragma unroll
      for (int r = 0; r < 4; ++r)
        sx[m][r] += __shfl_xor(sx[m][r], off, 64);
  if (l16 == 0) {
    #pragma unroll
    for (int m = 0; m < 3; ++m)
      #pragma unroll
      for (int r = 0; r < 4; ++r)
        reds[w][m * 16 + lhi * 4 + r] = sx[m][r];
  }
  __syncthreads();

  if (t < 48) {
    float mv = fmaxf(fmaxf(redm[0][t], redm[1][t]), fmaxf(redm[2][t], redm[3][t]));
    mv = (mv > -1e30f) ? mv : 0.f;
    float sv = reds[0][t] + reds[1][t] + reds[2][t] + reds[3][t];
    size_t o = (((size_t)chk * 128 + bh) * 48 + t) * 2;
    msums[o] = mv; msums[o + 1] = sv;
  }
  const size_t vbase = (size_t)bh * 131072;
  #pragma unroll
  for (int j = 0; j < 16; ++j) {
    int ll = w * 32 + 2 * j;
    u16 ua = vbf[vbase + (size_t)(l0 + ll) * 64 + lane];
    u16 ub = vbf[vbase + (size_t)(l0 + ll + 1) * 64 + lane];
    u32 pk = (u32)ua | ((u32)ub << 16);
    int s = ll >> 3;
    int sw = (s & 8) | ((s & 7) ^ (lane & 7));
    *reinterpret_cast<u32*>(&Bs[lane * 128 + (sw << 3) + (ll & 7)]) = pk;
  }
  __syncthreads();

  f32x4 acc2[3];
  #pragma unroll
  for (int m = 0; m < 3; ++m) acc2[m] = (f32x4){0.f, 0.f, 0.f, 0.f};
  #pragma unroll
  for (int ks = 0; ks < 4; ++ks) {
    bf16x8 b;
    { int cb = w * 16 + l16; int s = ks * 4 + lhi;
      int sw = (s & 8) | ((s & 7) ^ (cb & 7));
      b = *reinterpret_cast<const bf16x8*>(&Bs[cb * 128 + (sw << 3)]); }
    #pragma unroll
    for (int m = 0; m < 3; ++m) {
      int r = m * 16 + l16; int s = ks * 4 + lhi;
      int sw = (s & 8) | ((s & 7) ^ (r & 7));
      bf16x8 a = *reinterpret_cast<const bf16x8*>(&Ps[r * 128 + (sw << 3)]);
      acc2[m] = __builtin_amdgcn_mfma_f32_16x16x32_bf16(a, b, acc2[m], 0, 0, 0);
    }
  }
  #pragma unroll
  for (int m = 0; m < 3; ++m)
    #pragma unroll
    for (int r = 0; r < 4; ++r) {
      int u = m * 16 + lhi * 4 + r;
      partial[(((size_t)chk * 128 + bh) * 48 + u) * 64 + w * 16 + l16] = acc2[m][r];
    }
}

// ---------------- merge 16 chunk-partials with softmax rescale -> upd ---------------
__global__ __launch_bounds__(256)
void merge_pv(const float* __restrict__ partial, const float* __restrict__ msums,
              float* __restrict__ upd) {
  int tid = blockIdx.x * 256 + threadIdx.x;   // BH*U_*64
  int s = tid >> 6, d = tid & 63;
  int bh = s / U_, u = s - bh * U_;
  float mg = -INFINITY;
  #pragma unroll
  for (int c = 0; c < 16; ++c)
    mg = fmaxf(mg, msums[(((size_t)c * 128 + bh) * 48 + u) * 2]);
  float av = 0.f, sg = 0.f;
  #pragma unroll
  for (int c = 0; c < 16; ++c) {
    size_t o = (((size_t)c * 128 + bh) * 48 + u) * 2;
    float e = __expf(msums[o] - mg);
    av += partial[(((size_t)c * 128 + bh) * 48 + u) * 64 + d] * e;
    sg += msums[o + 1] * e;
  }
  upd[(size_t)s * 64 + d] = av / sg;
}

// ---------------- cumsum 2-phase over bf16 v -> bf16 ctx ----------------------------
__global__ __launch_bounds__(256)
void cumsumA(const u16* __restrict__ vbf, float* __restrict__ seg32) {
  int bh = blockIdx.x, sg = blockIdx.y;
  int t = threadIdx.x, w = t >> 6, lane = t & 63;
  int g = sg * 4 + w;
  size_t base = (size_t)bh * 131072 + (size_t)g * 32 * 64;
  float s = 0.f;
  for (int i = 0; i < 32; ++i) s += bf2f(vbf[base + i * 64 + lane]);
  seg32[((size_t)bh * 64 + g) * 64 + lane] = s;
}
__global__ __launch_bounds__(256)
void cumsumB(const u16* __restrict__ vbf, const float* __restrict__ seg32,
             u16* __restrict__ ctxbf) {
  int bh = blockIdx.x, sg = blockIdx.y;
  int t = threadIdx.x, w = t >> 6, lane = t & 63;
  int g = sg * 4 + w;
  float run = 0.f;
  for (int s = 0; s < g; ++s) run += seg32[((size_t)bh * 64 + s) * 64 + lane];
  size_t base = (size_t)bh * 131072 + (size_t)g * 32 * 64;
  for (int i = 0; i < 32; ++i) {
    run += bf2f(vbf[base + i * 64 + lane]);
    ctxbf[base + i * 64 + lane] = f2bf(run);
  }
}

// ---------------- scatter upd rows into bf16 ctx ------------------------------------
__global__ __launch_bounds__(256)
void scatter_kernel(const float* __restrict__ upd, const int* __restrict__ mtop,
                    u16* __restrict__ ctxbf) {
  int tid = blockIdx.x * 256 + threadIdx.x;
  int s = tid >> 6;
  if (s >= BH * U_) return;
  int d = tid & 63;
  int bh = s / U_;
  ctxbf[(size_t)bh * 131072 + (size_t)mtop[s] * 64 + d] = f2bf(upd[(size_t)s * 64 + d]);
}

// ---------------- Wo -> bf16, transposed + swizzled: WoT[j][512] --------------------
__global__ __launch_bounds__(256)
void wo_prep(const float* __restrict__ Wo, u16* __restrict__ WoT) {
  int tid = blockIdx.x * 256 + threadIdx.x;   // 32768
  int j = tid >> 9, k = tid & 511;
  float v = Wo[(size_t)k * 64 + j];
  int k0 = k & ~63, ko = k & 63;
  int ks = ko >> 5, kc = ko & 31;
  int slot = (ks * 4 + (kc >> 3)) ^ (j & 7);
  WoT[(size_t)j * 512 + k0 + (slot << 3) + (kc & 7)] = f2bf(v);
}

// ---------------- out GEMM (bf16 ctx): out[M][64] = ctx @ Wo ------------------------
__global__ __launch_bounds__(256, 6)
void gemm_out(const u16* __restrict__ ctxbf, const u16* __restrict__ WoT,
              float* __restrict__ out) {
  __shared__ u16 As[64 * 64];
  __shared__ u16 Bs[64 * 64];
  const int t = threadIdx.x, w = t >> 6, lane = t & 63;
  const int lhi = lane >> 4, l16 = lane & 15;
  const int row0 = blockIdx.x * 64;
  f32x4 acc[4];
  #pragma unroll
  for (int j = 0; j < 4; ++j) acc[j] = (f32x4){0.f, 0.f, 0.f, 0.f};

  for (int k0 = 0; k0 < 512; k0 += 64) {
    #pragma unroll
    for (int ii = 0; ii < 2; ++ii) {
      int e = t + ii * 256;
      int j = e >> 3, s = e & 7;
      gload16(WoT + (size_t)j * 512 + k0 + s * 8, Bs + (size_t)(w * 64 + ii * 256) * 8);
    }
    #pragma unroll
    for (int ii = 0; ii < 2; ++ii) {
      int e = t + ii * 256;
      int r = e >> 3, s = e & 7;
      gload16(ctxbf + (size_t)(row0 + r) * 512 + k0 + (s ^ (r & 7)) * 8,
              As + (size_t)(w * 64 + ii * 256) * 8);
    }
    __syncthreads();
    #pragma unroll
    for (int ks = 0; ks < 2; ++ks) {
      int r = w * 16 + l16;
      bf16x8 a = *reinterpret_cast<const bf16x8*>(
          &As[r * 64 + (((ks * 4 + lhi) ^ (r & 7)) << 3)]);
      #pragma unroll
      for (int jf = 0; jf < 4; ++jf) {
        int cb = jf * 16 + l16;
        bf16x8 b = *reinterpret_cast<const bf16x8*>(
            &Bs[cb * 64 + (((ks * 4 + lhi) ^ (cb & 7)) << 3)]);
        acc[jf] = __builtin_amdgcn_mfma_f32_16x16x32_bf16(a, b, acc[jf], 0, 0, 0);
      }
    }
    __syncthreads();
  }
  #pragma unroll
  for (int jf = 0; jf < 4; ++jf)
    #pragma unroll
    for (int r = 0; r < 4; ++r)
      out[(size_t)(row0 + w * 16 + lhi * 4 + r) * 64 + jf * 16 + l16] = acc[jf][r];
}

extern "C" void kernel_launch(void* const* d_in, const int* in_sizes, int n_in,
                              void* d_out, int out_size, void* d_ws, size_t ws_size,
                              hipStream_t stream) {
  const float* q_in = (const float*)d_in[0];
  const float* k_in = (const float*)d_in[1];
  const float* v_in = (const float*)d_in[2];
  const float* Wq   = (const float*)d_in[3];
  const float* Wk   = (const float*)d_in[4];
  const float* Wv   = (const float*)d_in[5];
  const float* Wo   = (const float*)d_in[6];
  const int*   indx = (const int*)d_in[7];
  float* out = (float*)d_out;

  float* ws = (float*)d_ws;
  float* qp   = ws;                         // [0, 16M) floats
  float* kp   = ws + 16777216;              // [16M, 32M)
  u16*   vbf  = (u16*)(ws + 33554432);      // 16M u16
  u64*   cand = (u64*)(ws + 50331648);      // 40960 u64
  u16*   WoT  = (u16*)cand;                 // after cand dead
  u16*   qredbf = (u16*)(ws + 50593792);
  int*   mtop = (int*)(ws + 50921472);
  u16*   Bt3  = (u16*)d_out;                // d_out scratch; gemm_out overwrites
  // qp region reuse (qp dead after gather_q):
  float* partial = qp;                      // 16*128*48*64 = 6,291,456 f
  float* msums   = qp + 6291456;            // 196,608 f
  float* upd     = qp + 6488064;            // 327,680 f
  // kp region reuse (kp dead after attn_fused):
  u16*   ctxbf = (u16*)kp;                  // 16M u16
  float* seg32 = kp + 8388608;              // 524,288 f

  const int M = B_ * L_;                    // 32768

  wsplit3_kernel<<<dim3(1024, 3), 256, 0, stream>>>(Wq, Wk, Wv, Bt3);

  // projections: q/k exact 3-term split single-buffer (f32 out), v plain bf16 dbuf
  gemm_proj3<<<1024, 256, 0, stream>>>(q_in, Bt3, qp);
  gemm_proj3<<<1024, 256, 0, stream>>>(k_in, Bt3 + 524288, kp);
  gemm_proj_v<<<1024, 256, 0, stream>>>(v_in, Bt3 + 1048576, vbf);

  // exact f32 dot + two-level top-40
  dotsel_kernel<<<dim3(BH, 8), 256, 0, stream>>>(qp, kp, indx, cand);
  merge_topk<<<BH, 64, 0, stream>>>(cand, mtop);
  gather_q_kernel<<<(BH * 48 * 64) / 256, 256, 0, stream>>>(qp, mtop, qredbf);

  // fused attention (QK^T + online softmax + PV partial) + rescale-merge
  attn_fused<<<dim3(BH, 16), 256, 0, stream>>>(qredbf, kp, vbf, mtop, partial, msums);
  merge_pv<<<(BH * U_ * 64) / 256, 256, 0, stream>>>(partial, msums, upd);

  // cumsum of v -> bf16 ctx (kp region; kp dead now)
  cumsumA<<<dim3(BH, 16), 256, 0, stream>>>(vbf, seg32);
  cumsumB<<<dim3(BH, 16), 256, 0, stream>>>(vbf, seg32, ctxbf);

  // scatter attention rows into ctx
  scatter_kernel<<<(BH * U_ * 64) / 256, 256, 0, stream>>>(upd, mtop, ctxbf);

  // out = ctx @ Wo (bf16 MFMA) — fully overwrites d_out (incl. Bt3 scratch)
  wo_prep<<<128, 256, 0, stream>>>(Wo, WoT);
  gemm_out<<<M / 64, 256, 0, stream>>>(ctxbf, WoT, out);
}

// Round 16
// 323.162 us; speedup vs baseline: 1.1621x; 1.0584x over previous
//
#include <hip/hip_runtime.h>
#include <hip/hip_bf16.h>
#include <math.h>

#define B_   16
#define L_   2048
#define DIN  512
#define HID_ 512
#define H_   8
#define D_   64
#define U_   40
#define BH   (B_*H_)     // 128

typedef unsigned short u16;
typedef unsigned int u32;
typedef unsigned long long u64;
typedef __bf16 bf16x8 __attribute__((ext_vector_type(8)));
typedef float f32x4 __attribute__((ext_vector_type(4)));

__device__ __forceinline__ u16 f2bf(float x) {            // RNE via HW cvt
  __bf16 b = (__bf16)x;
  return __builtin_bit_cast(unsigned short, b);
}
__device__ __forceinline__ float bf2f(u16 h) {
  return __uint_as_float(((unsigned)h) << 16);
}
__device__ __forceinline__ u32 pk2(float a, float b) {
  return (u32)f2bf(a) | ((u32)f2bf(b) << 16);
}
__device__ __forceinline__ void gload16(const u16* g, u16* l) {
  __builtin_amdgcn_global_load_lds(
      (__attribute__((address_space(1))) void*)(g),
      (__attribute__((address_space(3))) void*)(l), 16, 0, 0);
}
__device__ __forceinline__ void gload16f(const float* g, float* l) {
  __builtin_amdgcn_global_load_lds(
      (__attribute__((address_space(1))) void*)(g),
      (__attribute__((address_space(3))) void*)(l), 16, 0, 0);
}
__device__ __forceinline__ u64 mkkey(float Mv, int l) {
  u32 fb = __float_as_uint(Mv);
  u32 mapped = (fb & 0x80000000u) ? ~fb : (fb | 0x80000000u);
  return ((u64)mapped << 32) | (u64)(0xFFFFFFFFu - (u32)l);
}

// ---------------- weight split+transpose (all 3): W f32 -> Bt3[y] bf16 [512][1024] ---
__global__ __launch_bounds__(256)
void wsplit3_kernel(const float* __restrict__ Wq, const float* __restrict__ Wk,
                    const float* __restrict__ Wv, u16* __restrict__ Bt3) {
  const float* W = (blockIdx.y == 0) ? Wq : (blockIdx.y == 1) ? Wk : Wv;
  u16* Bt = Bt3 + (size_t)blockIdx.y * 524288;
  int tid = blockIdx.x * 256 + threadIdx.x;
  int n = tid & 511, k = tid >> 9;
  float a = W[(size_t)k * 512 + n];
  u16 hi = f2bf(a);
  u16 lo = f2bf(a - bf2f(hi));
  int kb = k >> 5, kc = k & 31;
  int slotH = kc >> 3, wi = kc & 7;
  int swzH = (slotH     ^ (n & 7)) << 3;
  int swzL = ((4+slotH) ^ (n & 7)) << 3;
  Bt[(size_t)n * 1024 + kb * 64 + swzH + wi] = hi;
  Bt[(size_t)n * 1024 + kb * 64 + swzL + wi] = lo;
}

// ---------------- q/k projection: 3-term split, dbuf + counted vmcnt (T4) -----------
// STAGE(kb+1) issued before compute(kb); raw s_barrier (NO implicit vmcnt(0) drain);
// asm vmcnt(8) waits only for STAGE(kb)'s loads, which had a full phase in flight.
__global__ __launch_bounds__(256, 2)
void gemm_proj3(const float* __restrict__ A, const u16* __restrict__ Bt,
                float* __restrict__ C) {
  __shared__ float Asf[2][128 * 32];
  __shared__ u16 Bs[2][128 * 64];
  const int bid = blockIdx.x;
  const int g = bid >> 3;
  const int xb = (bid & 7) + ((g >> 2) << 3);
  const int yb = g & 3;
  const int t = threadIdx.x;
  const int w = t >> 6, lane = t & 63;
  const int lhi = lane >> 4, l16 = lane & 15;
  const int row0 = xb * 128, col0 = yb * 128;
  const int wrow = (w >> 1) * 64, wcol = (w & 1) * 64;

  const u16* gB = Bt + (size_t)(col0 + w * 32 + (lane >> 3)) * 1024 + (lane & 7) * 8;
  const int rA0 = w * 32 + (lane >> 3);
  const int swsl = lane & 7;

  f32x4 acc[4][4];
  #pragma unroll
  for (int i = 0; i < 4; ++i)
    #pragma unroll
    for (int j = 0; j < 4; ++j) acc[i][j] = (f32x4){0.f, 0.f, 0.f, 0.f};

#define STAGE3(KB, NB)                                                          \
  { u16* lB = &Bs[NB][(w * 32) * 64];                                           \
    _Pragma("unroll") for (int i = 0; i < 4; ++i)                               \
      gload16(gB + (KB) * 64 + (size_t)i * 8 * 1024, lB + i * 8 * 64);          \
    _Pragma("unroll") for (int i = 0; i < 4; ++i) {                             \
      int r = rA0 + i * 8;                                                      \
      int slot = swsl ^ (r & 7);                                                \
      gload16f(A + (size_t)(row0 + r) * 512 + (KB) * 32 + slot * 4,             \
               &Asf[NB][(w * 32 + i * 8) * 32]); } }

  STAGE3(0, 0)
  asm volatile("s_waitcnt vmcnt(0)" ::: "memory");
  __builtin_amdgcn_s_barrier();

  for (int kb = 0; kb < 16; ++kb) {
    const int cur = kb & 1;
    if (kb < 15) {
      STAGE3(kb + 1, cur ^ 1)
      asm volatile("s_waitcnt vmcnt(8)" ::: "memory");
    } else {
      asm volatile("s_waitcnt vmcnt(0)" ::: "memory");
    }
    __builtin_amdgcn_sched_barrier(0);
    __builtin_amdgcn_s_barrier();

    bf16x8 bfH[4], bfL[4];
    #pragma unroll
    for (int j = 0; j < 4; ++j) {
      int cb = wcol + j * 16 + l16;
      bfH[j] = *reinterpret_cast<const bf16x8*>(
          &Bs[cur][cb * 64 + ((lhi ^ (cb & 7)) << 3)]);
      bfL[j] = *reinterpret_cast<const bf16x8*>(
          &Bs[cur][cb * 64 + (((4 + lhi) ^ (cb & 7)) << 3)]);
    }
    #pragma unroll
    for (int i = 0; i < 4; ++i) {
      int ra = wrow + i * 16 + l16;
      const f32x4 x0 = *reinterpret_cast<const f32x4*>(
          &Asf[cur][ra * 32 + (((lhi * 2)       ^ (ra & 7)) << 2)]);
      const f32x4 x1 = *reinterpret_cast<const f32x4*>(
          &Asf[cur][ra * 32 + ((((lhi * 2) + 1) ^ (ra & 7)) << 2)]);
      bf16x8 aH;
      aH[0] = (__bf16)x0[0]; aH[1] = (__bf16)x0[1];
      aH[2] = (__bf16)x0[2]; aH[3] = (__bf16)x0[3];
      aH[4] = (__bf16)x1[0]; aH[5] = (__bf16)x1[1];
      aH[6] = (__bf16)x1[2]; aH[7] = (__bf16)x1[3];
      #pragma unroll
      for (int j = 0; j < 4; ++j)
        acc[i][j] = __builtin_amdgcn_mfma_f32_16x16x32_bf16(aH, bfH[j], acc[i][j], 0, 0, 0);
      bf16x8 aL;
      aL[0] = (__bf16)(x0[0] - (float)aH[0]); aL[1] = (__bf16)(x0[1] - (float)aH[1]);
      aL[2] = (__bf16)(x0[2] - (float)aH[2]); aL[3] = (__bf16)(x0[3] - (float)aH[3]);
      aL[4] = (__bf16)(x1[0] - (float)aH[4]); aL[5] = (__bf16)(x1[1] - (float)aH[5]);
      aL[6] = (__bf16)(x1[2] - (float)aH[6]); aL[7] = (__bf16)(x1[3] - (float)aH[7]);
      #pragma unroll
      for (int j = 0; j < 4; ++j)
        acc[i][j] = __builtin_amdgcn_mfma_f32_16x16x32_bf16(aH, bfL[j], acc[i][j], 0, 0, 0);
      #pragma unroll
      for (int j = 0; j < 4; ++j)
        acc[i][j] = __builtin_amdgcn_mfma_f32_16x16x32_bf16(aL, bfH[j], acc[i][j], 0, 0, 0);
    }
    __builtin_amdgcn_s_barrier();
    __builtin_amdgcn_sched_barrier(0);
  }
#undef STAGE3
  #pragma unroll
  for (int i = 0; i < 4; ++i)
    #pragma unroll
    for (int j = 0; j < 4; ++j)
      #pragma unroll
      for (int r = 0; r < 4; ++r)
        C[(size_t)(row0 + wrow + i * 16 + lhi * 4 + r) * 512
          + col0 + wcol + j * 16 + l16] = acc[i][j][r];
}

// ---------------- v projection: plain bf16, dbuf + counted vmcnt --------------------
__global__ __launch_bounds__(256, 2)
void gemm_proj_v(const float* __restrict__ A, const u16* __restrict__ Bt,
                 u16* __restrict__ C) {
  __shared__ float Asf[2][128 * 32];
  __shared__ u16 Bs[2][128 * 64];
  const int bid = blockIdx.x;
  const int g = bid >> 3;
  const int xb = (bid & 7) + ((g >> 2) << 3);
  const int yb = g & 3;
  const int t = threadIdx.x;
  const int w = t >> 6, lane = t & 63;
  const int lhi = lane >> 4, l16 = lane & 15;
  const int row0 = xb * 128, col0 = yb * 128;
  const int wrow = (w >> 1) * 64, wcol = (w & 1) * 64;

  const u16* gB = Bt + (size_t)(col0 + w * 32 + (lane >> 3)) * 1024 + (lane & 7) * 8;
  const int rA0 = w * 32 + (lane >> 3);
  const int swsl = lane & 7;

  f32x4 acc[4][4];
  #pragma unroll
  for (int i = 0; i < 4; ++i)
    #pragma unroll
    for (int j = 0; j < 4; ++j) acc[i][j] = (f32x4){0.f, 0.f, 0.f, 0.f};

#define STAGEV(KB, NB)                                                          \
  { u16* lB = &Bs[NB][(w * 32) * 64];                                           \
    _Pragma("unroll") for (int i = 0; i < 4; ++i)                               \
      gload16(gB + (KB) * 64 + (size_t)i * 8 * 1024, lB + i * 8 * 64);          \
    _Pragma("unroll") for (int i = 0; i < 4; ++i) {                             \
      int r = rA0 + i * 8;                                                      \
      int slot = swsl ^ (r & 7);                                                \
      gload16f(A + (size_t)(row0 + r) * 512 + (KB) * 32 + slot * 4,             \
               &Asf[NB][(w * 32 + i * 8) * 32]); } }

  STAGEV(0, 0)
  asm volatile("s_waitcnt vmcnt(0)" ::: "memory");
  __builtin_amdgcn_s_barrier();

  for (int kb = 0; kb < 16; ++kb) {
    const int cur = kb & 1;
    if (kb < 15) {
      STAGEV(kb + 1, cur ^ 1)
      asm volatile("s_waitcnt vmcnt(8)" ::: "memory");
    } else {
      asm volatile("s_waitcnt vmcnt(0)" ::: "memory");
    }
    __builtin_amdgcn_sched_barrier(0);
    __builtin_amdgcn_s_barrier();

    bf16x8 bfH[4];
    #pragma unroll
    for (int j = 0; j < 4; ++j) {
      int cb = wcol + j * 16 + l16;
      bfH[j] = *reinterpret_cast<const bf16x8*>(
          &Bs[cur][cb * 64 + ((lhi ^ (cb & 7)) << 3)]);
    }
    #pragma unroll
    for (int i = 0; i < 4; ++i) {
      int ra = wrow + i * 16 + l16;
      const f32x4 x0 = *reinterpret_cast<const f32x4*>(
          &Asf[cur][ra * 32 + (((lhi * 2)       ^ (ra & 7)) << 2)]);
      const f32x4 x1 = *reinterpret_cast<const f32x4*>(
          &Asf[cur][ra * 32 + ((((lhi * 2) + 1) ^ (ra & 7)) << 2)]);
      bf16x8 aH;
      aH[0] = (__bf16)x0[0]; aH[1] = (__bf16)x0[1];
      aH[2] = (__bf16)x0[2]; aH[3] = (__bf16)x0[3];
      aH[4] = (__bf16)x1[0]; aH[5] = (__bf16)x1[1];
      aH[6] = (__bf16)x1[2]; aH[7] = (__bf16)x1[3];
      #pragma unroll
      for (int j = 0; j < 4; ++j)
        acc[i][j] = __builtin_amdgcn_mfma_f32_16x16x32_bf16(aH, bfH[j], acc[i][j], 0, 0, 0);
    }
    __builtin_amdgcn_s_barrier();
    __builtin_amdgcn_sched_barrier(0);
  }
#undef STAGEV
  #pragma unroll
  for (int i = 0; i < 4; ++i)
    #pragma unroll
    for (int j = 0; j < 4; ++j)
      #pragma unroll
      for (int r = 0; r < 4; ++r)
        C[(size_t)(row0 + wrow + i * 16 + lhi * 4 + r) * 512
          + col0 + wcol + j * 16 + l16] = f2bf(acc[i][j][r]);
}

// ---------------- dot + per-chunk top-40 candidates (exact f32) ---------------------
__global__ __launch_bounds__(256)
void dotsel_kernel(const float* __restrict__ qp, const float* __restrict__ kp,
                   const int* __restrict__ indx, u64* __restrict__ cand) {
  __shared__ u64 keys[256];
  __shared__ u64 wmax[2][4];
  const int bh = blockIdx.x, ch = blockIdx.y;
  const int t = threadIdx.x, w = t >> 6, lane = t & 63;
  const size_t boff = (size_t)bh * 131072;
  const int l0 = ch * 256 + w * 64;
  const float cUL = 40.0f / 2048.0f;
  const int li = lane >> 4;
  const int dq = lane & 15;

  #pragma unroll 8
  for (int i = 0; i < 16; ++i) {
    int l = l0 + i * 4 + li;
    int ls = indx[l];
    float4 q4 = *reinterpret_cast<const float4*>(&qp[boff + (size_t)l * 64 + dq * 4]);
    float4 k4 = *reinterpret_cast<const float4*>(&kp[boff + (size_t)ls * 64 + dq * 4]);
    float p = q4.x * k4.x + q4.y * k4.y + q4.z * k4.z + q4.w * k4.w;
    p += __shfl_xor(p, 1, 64);
    p += __shfl_xor(p, 2, 64);
    p += __shfl_xor(p, 4, 64);
    p += __shfl_xor(p, 8, 64);
    if (dq == 0) {
      float Mv = p - p * cUL;
      keys[w * 64 + i * 4 + li] = mkkey(Mv, l);
    }
  }
  __syncthreads();

  u64 myk = keys[t];
  for (int u = 0; u < U_; ++u) {
    u64 b = myk;
    #pragma unroll
    for (int off = 32; off >= 1; off >>= 1) {
      u64 v = __shfl_xor(b, off, 64);
      if (v > b) b = v;
    }
    if (lane == 0) wmax[u & 1][w] = b;
    __syncthreads();
    const u64* wm = wmax[u & 1];
    u64 m = wm[0];
    if (wm[1] > m) m = wm[1];
    if (wm[2] > m) m = wm[2];
    if (wm[3] > m) m = wm[3];
    if (myk == m) myk = 0;              // unique keys: owner clears
    if (t == 0) cand[((size_t)(bh * 8 + ch)) * U_ + u] = m;
  }
}

// ---------------- merge 8x40 candidates -> top-40 + fold wo_prep --------------------
__global__ __launch_bounds__(256)
void merge_topk_wo(const u64* __restrict__ cand, int* __restrict__ mtop,
                   const float* __restrict__ Wo, u16* __restrict__ WoT) {
  const int bh = blockIdx.x;          // 128 blocks
  const int t = threadIdx.x;
  // wo_prep slice: tid over 128*256 = 32768
  {
    int tid = bh * 256 + t;
    int j = tid >> 9, k = tid & 511;
    float v = Wo[(size_t)k * 64 + j];
    int k0 = k & ~63, ko = k & 63;
    int ks = ko >> 5, kc = ko & 31;
    int slot = (ks * 4 + (kc >> 3)) ^ (j & 7);
    WoT[(size_t)j * 512 + k0 + (slot << 3) + (kc & 7)] = f2bf(v);
  }
  if (t >= 64) return;
  const int lane = t;
  u64 c0 = cand[(size_t)bh * 320 + 0 * 64 + lane];
  u64 c1 = cand[(size_t)bh * 320 + 1 * 64 + lane];
  u64 c2 = cand[(size_t)bh * 320 + 2 * 64 + lane];
  u64 c3 = cand[(size_t)bh * 320 + 3 * 64 + lane];
  u64 c4 = cand[(size_t)bh * 320 + 4 * 64 + lane];
  for (int u = 0; u < U_; ++u) {
    u64 b = c0;
    if (c1 > b) b = c1;
    if (c2 > b) b = c2;
    if (c3 > b) b = c3;
    if (c4 > b) b = c4;
    #pragma unroll
    for (int off = 32; off >= 1; off >>= 1) {
      u64 v = __shfl_xor(b, off, 64);
      if (v > b) b = v;
    }
    if (c0 == b) c0 = 0;
    if (c1 == b) c1 = 0;
    if (c2 == b) c2 = 0;
    if (c3 == b) c3 = 0;
    if (c4 == b) c4 = 0;
    if (lane == 0) mtop[bh * U_ + u] = (int)(0xFFFFFFFFu - (u32)b);
  }
}

// ---------------- gather selected q rows -> bf16, x0.125, 48-row padded -------------
__global__ __launch_bounds__(256)
void gather_q_kernel(const float* __restrict__ qp, const int* __restrict__ mtop,
                     u16* __restrict__ qredbf) {
  int tid = blockIdx.x * 256 + threadIdx.x;   // BH*48*64 total
  int s = tid >> 6;
  int d = tid & 63;
  int bh = s / 48;
  int u = s - bh * 48;
  float val = 0.f;
  if (u < U_) {
    int m = mtop[bh * U_ + u];
    val = qp[(size_t)bh * (L_ * D_) + (size_t)m * D_ + d] * 0.125f;
  }
  qredbf[tid] = f2bf(val);
}

// ---------------- fused attention chunk: QK^T -> online softmax -> PV partial -------
__global__ __launch_bounds__(256)
void attn_fused(const u16* __restrict__ qredbf, const float* __restrict__ kp,
                const u16* __restrict__ vbf, const int* __restrict__ mtop,
                float* __restrict__ partial, float* __restrict__ msums) {
  __shared__ u16 As[48 * 64];
  __shared__ u16 Bs[128 * 64];      // K tile; reused as V^T [64][128]
  __shared__ u16 Ps[48 * 128];
  __shared__ int ms[48];
  __shared__ float redm[4][48];
  __shared__ float reds[4][48];
  const int bh = blockIdx.x, chk = blockIdx.y;
  const int l0 = chk * 128;
  const int t = threadIdx.x, w = t >> 6, lane = t & 63;
  const int lhi = lane >> 4, l16 = lane & 15;

  for (int e = t; e < 384; e += 256) {
    int r = e >> 3, s = e & 7;
    *reinterpret_cast<uint4*>(&As[r * 64 + ((s ^ (r & 7)) << 3)]) =
        *reinterpret_cast<const uint4*>(&qredbf[(size_t)bh * 3072 + e * 8]);
  }
  #pragma unroll
  for (int ee = 0; ee < 4; ++ee) {
    int e = t + ee * 256;
    int r = e >> 3, s = e & 7;
    const float* src = &kp[(size_t)bh * 131072 + (size_t)(l0 + r) * 64 + s * 8];
    float4 va = *reinterpret_cast<const float4*>(src);
    float4 vb = *reinterpret_cast<const float4*>(src + 4);
    uint4 w4 = make_uint4(pk2(va.x, va.y), pk2(va.z, va.w),
                          pk2(vb.x, vb.y), pk2(vb.z, vb.w));
    *reinterpret_cast<uint4*>(&Bs[r * 64 + ((s ^ (r & 7)) << 3)]) = w4;
  }
  if (t < 48) ms[t] = (t < U_) ? mtop[bh * U_ + t] : -1;
  __syncthreads();

  f32x4 acc[3][2];
  #pragma unroll
  for (int m = 0; m < 3; ++m)
    #pragma unroll
    for (int n = 0; n < 2; ++n) acc[m][n] = (f32x4){0.f, 0.f, 0.f, 0.f};
  #pragma unroll
  for (int ks = 0; ks < 2; ++ks) {
    bf16x8 a[3], b[2];
    #pragma unroll
    for (int m = 0; m < 3; ++m) {
      int r = m * 16 + l16;
      a[m] = *reinterpret_cast<const bf16x8*>(
          &As[r * 64 + (((ks * 4 + lhi) ^ (r & 7)) << 3)]);
    }
    #pragma unroll
    for (int n = 0; n < 2; ++n) {
      int cb = w * 32 + n * 16 + l16;
      b[n] = *reinterpret_cast<const bf16x8*>(
          &Bs[cb * 64 + (((ks * 4 + lhi) ^ (cb & 7)) << 3)]);
    }
    #pragma unroll
    for (int m = 0; m < 3; ++m)
      #pragma unroll
      for (int n = 0; n < 2; ++n)
        acc[m][n] = __builtin_amdgcn_mfma_f32_16x16x32_bf16(a[m], b[n], acc[m][n], 0, 0, 0);
  }

  float val[3][2][4], mx[3][4];
  #pragma unroll
  for (int m = 0; m < 3; ++m)
    #pragma unroll
    for (int r = 0; r < 4; ++r) {
      int u = m * 16 + lhi * 4 + r;
      float v0 = acc[m][0][r], v1 = acc[m][1][r];
      if (l0 + w * 32 + 0 * 16 + l16 > ms[u]) v0 = -INFINITY;
      if (l0 + w * 32 + 1 * 16 + l16 > ms[u]) v1 = -INFINITY;
      val[m][0][r] = v0; val[m][1][r] = v1;
      mx[m][r] = fmaxf(v0, v1);
    }
  #pragma unroll
  for (int off = 1; off <= 8; off <<= 1)
    #pragma unroll
    for (int m = 0; m < 3; ++m)
      #pragma unroll
      for (int r = 0; r < 4; ++r)
        mx[m][r] = fmaxf(mx[m][r], __shfl_xor(mx[m][r], off, 64));
  if (l16 == 0) {
    #pragma unroll
    for (int m = 0; m < 3; ++m)
      #pragma unroll
      for (int r = 0; r < 4; ++r)
        redm[w][m * 16 + lhi * 4 + r] = mx[m][r];
  }
  __syncthreads();

  float sx[3][4];
  #pragma unroll
  for (int m = 0; m < 3; ++m)
    #pragma unroll
    for (int r = 0; r < 4; ++r) {
      int u = m * 16 + lhi * 4 + r;
      float mv = fmaxf(fmaxf(redm[0][u], redm[1][u]), fmaxf(redm[2][u], redm[3][u]));
      mv = (mv > -1e30f) ? mv : 0.f;
      float p0 = __expf(val[m][0][r] - mv);
      float p1 = __expf(val[m][1][r] - mv);
      sx[m][r] = p0 + p1;
      {
        int l = w * 32 + 0 * 16 + l16, s = l >> 3;
        int sw = (s & 8) | ((s & 7) ^ (u & 7));
        Ps[u * 128 + (sw << 3) + (l & 7)] = f2bf(p0);
      }
      {
        int l = w * 32 + 1 * 16 + l16, s = l >> 3;
        int sw = (s & 8) | ((s & 7) ^ (u & 7));
        Ps[u * 128 + (sw << 3) + (l & 7)] = f2bf(p1);
      }
    }
  #pragma unroll
  for (int off = 1; off <= 8; off <<= 1)
    #pragma unroll
    for (int m = 0; m < 3; ++m)
      #pragma unroll
      for (int r = 0; r < 4; ++r)
        sx[m][r] += __shfl_xor(sx[m][r], off, 64);
  if (l16 == 0) {
    #pragma unroll
    for (int m = 0; m < 3; ++m)
      #pragma unroll
      for (int r = 0; r < 4; ++r)
        reds[w][m * 16 + lhi * 4 + r] = sx[m][r];
  }
  __syncthreads();

  if (t < 48) {
    float mv = fmaxf(fmaxf(redm[0][t], redm[1][t]), fmaxf(redm[2][t], redm[3][t]));
    mv = (mv > -1e30f) ? mv : 0.f;
    float sv = reds[0][t] + reds[1][t] + reds[2][t] + reds[3][t];
    size_t o = (((size_t)chk * 128 + bh) * 48 + t) * 2;
    msums[o] = mv; msums[o + 1] = sv;
  }
  const size_t vbase = (size_t)bh * 131072;
  #pragma unroll
  for (int j = 0; j < 16; ++j) {
    int ll = w * 32 + 2 * j;
    u16 ua = vbf[vbase + (size_t)(l0 + ll) * 64 + lane];
    u16 ub = vbf[vbase + (size_t)(l0 + ll + 1) * 64 + lane];
    u32 pk = (u32)ua | ((u32)ub << 16);
    int s = ll >> 3;
    int sw = (s & 8) | ((s & 7) ^ (lane & 7));
    *reinterpret_cast<u32*>(&Bs[lane * 128 + (sw << 3) + (ll & 7)]) = pk;
  }
  __syncthreads();

  f32x4 acc2[3];
  #pragma unroll
  for (int m = 0; m < 3; ++m) acc2[m] = (f32x4){0.f, 0.f, 0.f, 0.f};
  #pragma unroll
  for (int ks = 0; ks < 4; ++ks) {
    bf16x8 b;
    { int cb = w * 16 + l16; int s = ks * 4 + lhi;
      int sw = (s & 8) | ((s & 7) ^ (cb & 7));
      b = *reinterpret_cast<const bf16x8*>(&Bs[cb * 128 + (sw << 3)]); }
    #pragma unroll
    for (int m = 0; m < 3; ++m) {
      int r = m * 16 + l16; int s = ks * 4 + lhi;
      int sw = (s & 8) | ((s & 7) ^ (r & 7));
      bf16x8 a = *reinterpret_cast<const bf16x8*>(&Ps[r * 128 + (sw << 3)]);
      acc2[m] = __builtin_amdgcn_mfma_f32_16x16x32_bf16(a, b, acc2[m], 0, 0, 0);
    }
  }
  #pragma unroll
  for (int m = 0; m < 3; ++m)
    #pragma unroll
    for (int r = 0; r < 4; ++r) {
      int u = m * 16 + lhi * 4 + r;
      partial[(((size_t)chk * 128 + bh) * 48 + u) * 64 + w * 16 + l16] = acc2[m][r];
    }
}

// ---------------- cumsum 2-phase over bf16 v -> bf16 ctx ----------------------------
__global__ __launch_bounds__(256)
void cumsumA(const u16* __restrict__ vbf, float* __restrict__ seg32) {
  int bh = blockIdx.x, sg = blockIdx.y;
  int t = threadIdx.x, w = t >> 6, lane = t & 63;
  int g = sg * 4 + w;
  size_t base = (size_t)bh * 131072 + (size_t)g * 32 * 64;
  float s = 0.f;
  for (int i = 0; i < 32; ++i) s += bf2f(vbf[base + i * 64 + lane]);
  seg32[((size_t)bh * 64 + g) * 64 + lane] = s;
}
__global__ __launch_bounds__(256)
void cumsumB(const u16* __restrict__ vbf, const float* __restrict__ seg32,
             u16* __restrict__ ctxbf) {
  int bh = blockIdx.x, sg = blockIdx.y;
  int t = threadIdx.x, w = t >> 6, lane = t & 63;
  int g = sg * 4 + w;
  float run = 0.f;
  for (int s = 0; s < g; ++s) run += seg32[((size_t)bh * 64 + s) * 64 + lane];
  size_t base = (size_t)bh * 131072 + (size_t)g * 32 * 64;
  for (int i = 0; i < 32; ++i) {
    run += bf2f(vbf[base + i * 64 + lane]);
    ctxbf[base + i * 64 + lane] = f2bf(run);
  }
}

// ---------------- merge 16 chunk-partials + rescale, scatter into ctx ---------------
__global__ __launch_bounds__(256)
void merge_pv_scatter(const float* __restrict__ partial, const float* __restrict__ msums,
                      const int* __restrict__ mtop, u16* __restrict__ ctxbf) {
  int tid = blockIdx.x * 256 + threadIdx.x;   // BH*U_*64
  int s = tid >> 6, d = tid & 63;
  int bh = s / U_, u = s - bh * U_;
  float mg = -INFINITY;
  #pragma unroll
  for (int c = 0; c < 16; ++c)
    mg = fmaxf(mg, msums[(((size_t)c * 128 + bh) * 48 + u) * 2]);
  float av = 0.f, sg = 0.f;
  #pragma unroll
  for (int c = 0; c < 16; ++c) {
    size_t o = (((size_t)c * 128 + bh) * 48 + u) * 2;
    float e = __expf(msums[o] - mg);
    av += partial[(((size_t)c * 128 + bh) * 48 + u) * 64 + d] * e;
    sg += msums[o + 1] * e;
  }
  ctxbf[(size_t)bh * 131072 + (size_t)mtop[s] * 64 + d] = f2bf(av / sg);
}

// ---------------- out GEMM (bf16 ctx): out[M][64] = ctx @ Wo ------------------------
__global__ __launch_bounds__(256, 6)
void gemm_out(const u16* __restrict__ ctxbf, const u16* __restrict__ WoT,
              float* __restrict__ out) {
  __shared__ u16 As[64 * 64];
  __shared__ u16 Bs[64 * 64];
  const int t = threadIdx.x, w = t >> 6, lane = t & 63;
  const int lhi = lane >> 4, l16 = lane & 15;
  const int row0 = blockIdx.x * 64;
  f32x4 acc[4];
  #pragma unroll
  for (int j = 0; j < 4; ++j) acc[j] = (f32x4){0.f, 0.f, 0.f, 0.f};

  for (int k0 = 0; k0 < 512; k0 += 64) {
    #pragma unroll
    for (int ii = 0; ii < 2; ++ii) {
      int e = t + ii * 256;
      int j = e >> 3, s = e & 7;
      gload16(WoT + (size_t)j * 512 + k0 + s * 8, Bs + (size_t)(w * 64 + ii * 256) * 8);
    }
    #pragma unroll
    for (int ii = 0; ii < 2; ++ii) {
      int e = t + ii * 256;
      int r = e >> 3, s = e & 7;
      gload16(ctxbf + (size_t)(row0 + r) * 512 + k0 + (s ^ (r & 7)) * 8,
              As + (size_t)(w * 64 + ii * 256) * 8);
    }
    __syncthreads();
    #pragma unroll
    for (int ks = 0; ks < 2; ++ks) {
      int r = w * 16 + l16;
      bf16x8 a = *reinterpret_cast<const bf16x8*>(
          &As[r * 64 + (((ks * 4 + lhi) ^ (r & 7)) << 3)]);
      #pragma unroll
      for (int jf = 0; jf < 4; ++jf) {
        int cb = jf * 16 + l16;
        bf16x8 b = *reinterpret_cast<const bf16x8*>(
            &Bs[cb * 64 + (((ks * 4 + lhi) ^ (cb & 7)) << 3)]);
        acc[jf] = __builtin_amdgcn_mfma_f32_16x16x32_bf16(a, b, acc[jf], 0, 0, 0);
      }
    }
    __syncthreads();
  }
  #pragma unroll
  for (int jf = 0; jf < 4; ++jf)
    #pragma unroll
    for (int r = 0; r < 4; ++r)
      out[(size_t)(row0 + w * 16 + lhi * 4 + r) * 64 + jf * 16 + l16] = acc[jf][r];
}

extern "C" void kernel_launch(void* const* d_in, const int* in_sizes, int n_in,
                              void* d_out, int out_size, void* d_ws, size_t ws_size,
                              hipStream_t stream) {
  const float* q_in = (const float*)d_in[0];
  const float* k_in = (const float*)d_in[1];
  const float* v_in = (const float*)d_in[2];
  const float* Wq   = (const float*)d_in[3];
  const float* Wk   = (const float*)d_in[4];
  const float* Wv   = (const float*)d_in[5];
  const float* Wo   = (const float*)d_in[6];
  const int*   indx = (const int*)d_in[7];
  float* out = (float*)d_out;

  float* ws = (float*)d_ws;
  float* qp   = ws;                         // [0, 16M) floats
  float* kp   = ws + 16777216;              // [16M, 32M)
  u16*   vbf  = (u16*)(ws + 33554432);      // 16M u16
  u64*   cand = (u64*)(ws + 50331648);      // 40960 u64 -> ends 50413568
  u16*   qredbf = (u16*)(ws + 50593792);    // 393216 u16 -> ends 50790400
  u16*   WoT  = (u16*)(ws + 50790400);      // 32768 u16 (in gap; no alias with cand)
  int*   mtop = (int*)(ws + 50921472);
  u16*   Bt3  = (u16*)d_out;                // d_out scratch; gemm_out overwrites
  // qp region reuse (qp dead after gather_q):
  float* partial = qp;                      // 6,291,456 f
  float* msums   = qp + 6291456;            // 196,608 f
  // kp region reuse (kp dead after attn_fused):
  u16*   ctxbf = (u16*)kp;                  // 16M u16
  float* seg32 = kp + 8388608;              // 524,288 f

  const int M = B_ * L_;                    // 32768

  wsplit3_kernel<<<dim3(1024, 3), 256, 0, stream>>>(Wq, Wk, Wv, Bt3);

  // projections: q/k 3-term split dbuf+counted-vmcnt, v plain bf16 dbuf+counted-vmcnt
  gemm_proj3<<<1024, 256, 0, stream>>>(q_in, Bt3, qp);
  gemm_proj3<<<1024, 256, 0, stream>>>(k_in, Bt3 + 524288, kp);
  gemm_proj_v<<<1024, 256, 0, stream>>>(v_in, Bt3 + 1048576, vbf);

  // exact f32 dot + two-level top-40 (+ folded wo_prep)
  dotsel_kernel<<<dim3(BH, 8), 256, 0, stream>>>(qp, kp, indx, cand);
  merge_topk_wo<<<BH, 256, 0, stream>>>(cand, mtop, Wo, WoT);
  gather_q_kernel<<<(BH * 48 * 64) / 256, 256, 0, stream>>>(qp, mtop, qredbf);

  // fused attention (QK^T + online softmax + PV partial)
  attn_fused<<<dim3(BH, 16), 256, 0, stream>>>(qredbf, kp, vbf, mtop, partial, msums);

  // cumsum of v -> bf16 ctx, then merge+scatter attention rows directly into ctx
  cumsumA<<<dim3(BH, 16), 256, 0, stream>>>(vbf, seg32);
  cumsumB<<<dim3(BH, 16), 256, 0, stream>>>(vbf, seg32, ctxbf);
  merge_pv_scatter<<<(BH * U_ * 64) / 256, 256, 0, stream>>>(partial, msums, mtop, ctxbf);

  // out = ctx @ Wo (bf16 MFMA) — fully overwrites d_out (incl. Bt3 scratch)
  gemm_out<<<M / 64, 256, 0, stream>>>(ctxbf, WoT, out);
}